// Round 1
// baseline (3300.418 us; speedup 1.0000x reference)
//
#include <hip/hip_runtime.h>

#define NN 100000
#define NE 1600000
#define NG 128
#define HID 128
#define NC 10

// ---------------- histogram of src/dst degrees ----------------
__global__ __launch_bounds__(256) void hist_k(const int* __restrict__ src,
                                              const int* __restrict__ dst,
                                              int* __restrict__ cnt_out,
                                              int* __restrict__ cnt_in) {
    int e = blockIdx.x * 256 + threadIdx.x;
    if (e < NE) {
        atomicAdd(&cnt_out[src[e]], 1);
        atomicAdd(&cnt_in[dst[e]], 1);
    }
}

// ---------------- exclusive scan of in-degree -> row_start ----------------
__global__ __launch_bounds__(1024) void scan_k(const int* __restrict__ cnt,
                                               int* __restrict__ row_start) {
    __shared__ int wsum[16];
    __shared__ int carry;
    int t = threadIdx.x;
    int lane = t & 63, wid = t >> 6;
    int offset = 0;
    for (int base = 0; base < NN; base += 1024) {
        int idx = base + t;
        int v = (idx < NN) ? cnt[idx] : 0;
        int x = v;
#pragma unroll
        for (int d = 1; d < 64; d <<= 1) {
            int y = __shfl_up(x, d, 64);
            if (lane >= d) x += y;
        }
        if (lane == 63) wsum[wid] = x;
        __syncthreads();
        if (t == 0) {
            int s = 0;
#pragma unroll
            for (int i = 0; i < 16; i++) { int tmp = wsum[i]; wsum[i] = s; s += tmp; }
            carry = s;
        }
        __syncthreads();
        int excl = offset + wsum[wid] + (x - v);
        if (idx < NN) row_start[idx] = excl;
        offset += carry;
        __syncthreads();
    }
    if (t == 0) row_start[NN] = offset;
}

// ---------------- per-node: cs, cd, h0*cs, cursor init ----------------
__global__ __launch_bounds__(256) void node_prep_k(const int* __restrict__ cnt_out,
                                                   const int* __restrict__ cnt_in,
                                                   const int* __restrict__ row_start,
                                                   float* __restrict__ cs,
                                                   float* __restrict__ cd,
                                                   float* __restrict__ s0,
                                                   int* __restrict__ cursor) {
    int n = blockIdx.x * 256 + threadIdx.x;
    if (n < NN) {
        float od = (float)cnt_out[n];
        float idg = (float)cnt_in[n];
        float c_s = rsqrtf(fmaxf(od, 1.f));
        float c_d = rsqrtf(fmaxf(idg, 1.f));
        cs[n] = c_s;
        cd[n] = c_d;
        s0[n] = idg * c_s;   // h0 * cs  (h0 = in_deg)
        cursor[n] = row_start[n];
    }
}

// ---------------- CSC fill: group edge srcs by dst ----------------
__global__ __launch_bounds__(256) void fill_k(const int* __restrict__ src,
                                              const int* __restrict__ dst,
                                              int* __restrict__ cursor,
                                              int* __restrict__ col) {
    int e = blockIdx.x * 256 + threadIdx.x;
    if (e < NE) {
        int d = dst[e];
        int pos = atomicAdd(&cursor[d], 1);
        col[pos] = src[e];
    }
}

// ---------------- layer-1 scalar aggregation ----------------
__global__ __launch_bounds__(256) void l1_agg_k(const int* __restrict__ row_start,
                                                const int* __restrict__ col,
                                                const float* __restrict__ s0,
                                                const float* __restrict__ cd,
                                                float* __restrict__ aggs) {
    int n = blockIdx.x * 256 + threadIdx.x;
    if (n < NN) {
        int b = row_start[n], e = row_start[n + 1];
        float a = 0.f;
        for (int i = b; i < e; i++) a += s0[col[i]];
        aggs[n] = a * cd[n];
    }
}

// ---------------- layer-1 rank-1 expand: h = relu(aggs*W1 + b1) ----------------
__global__ __launch_bounds__(256) void l1_expand_k(const float* __restrict__ aggs,
                                                   const float* __restrict__ W1,
                                                   const float* __restrict__ b1,
                                                   float* __restrict__ h) {
    int i = blockIdx.x * 256 + threadIdx.x;   // grid covers NN*HID exactly
    int f = i & (HID - 1);
    int n = i >> 7;
    h[i] = fmaxf(aggs[n] * W1[f] + b1[f], 0.f);
}

// ---------------- GEMM: p[n] = cs[n] * (h[n] @ W), fp32 ----------------
__global__ __launch_bounds__(256) void gemm_k(const float* __restrict__ h,
                                              const float* __restrict__ W,
                                              const float* __restrict__ cs,
                                              float* __restrict__ p) {
    __shared__ float Wl[HID * HID];   // 64 KB
    int t = threadIdx.x;
    for (int i = t * 4; i < HID * HID; i += 256 * 4) {
        *(float4*)&Wl[i] = *(const float4*)&W[i];
    }
    __syncthreads();

    int n0 = blockIdx.x * 64 + (t >> 5) * 8;
    int c0 = (t & 31) * 4;

    float4 acc[8];
#pragma unroll
    for (int i = 0; i < 8; i++) acc[i] = make_float4(0.f, 0.f, 0.f, 0.f);

    const float* hp[8];
    bool valid[8];
#pragma unroll
    for (int i = 0; i < 8; i++) {
        int n = n0 + i;
        valid[i] = (n < NN);
        hp[i] = h + (size_t)(valid[i] ? n : 0) * HID;
    }

    for (int k = 0; k < HID; k += 4) {
        float4 w0 = *(float4*)&Wl[(k + 0) * HID + c0];
        float4 w1 = *(float4*)&Wl[(k + 1) * HID + c0];
        float4 w2 = *(float4*)&Wl[(k + 2) * HID + c0];
        float4 w3 = *(float4*)&Wl[(k + 3) * HID + c0];
#pragma unroll
        for (int i = 0; i < 8; i++) {
            float4 a = *(const float4*)(hp[i] + k);
            acc[i].x += a.x * w0.x + a.y * w1.x + a.z * w2.x + a.w * w3.x;
            acc[i].y += a.x * w0.y + a.y * w1.y + a.z * w2.y + a.w * w3.y;
            acc[i].z += a.x * w0.z + a.y * w1.z + a.z * w2.z + a.w * w3.z;
            acc[i].w += a.x * w0.w + a.y * w1.w + a.z * w2.w + a.w * w3.w;
        }
    }

#pragma unroll
    for (int i = 0; i < 8; i++) {
        int n = n0 + i;
        if (valid[i]) {
            float s = cs[n];
            float4 r = acc[i];
            r.x *= s; r.y *= s; r.z *= s; r.w *= s;
            *(float4*)&p[(size_t)n * HID + c0] = r;
        }
    }
}

// ---------------- aggregate p over incoming edges, relu epilogue ----------------
__global__ __launch_bounds__(256) void agg_relu_k(const float* __restrict__ p,
                                                  const int* __restrict__ row_start,
                                                  const int* __restrict__ col,
                                                  const float* __restrict__ cd,
                                                  const float* __restrict__ b,
                                                  float* __restrict__ h) {
    int n = blockIdx.x * 2 + (threadIdx.x >> 7);
    int f = threadIdx.x & (HID - 1);
    int beg = row_start[n], end = row_start[n + 1];
    float a = 0.f;
    for (int i = beg; i < end; i++) {
        a += p[(size_t)col[i] * HID + f];
    }
    h[(size_t)n * HID + f] = fmaxf(a * cd[n] + b[f], 0.f);
}

// ---------------- mean-pool per graph (seg sorted) ----------------
#define POOL_CHUNK 512
__global__ __launch_bounds__(128) void pool_k(const float* __restrict__ h,
                                              const int* __restrict__ seg,
                                              float* __restrict__ hg_sum,
                                              float* __restrict__ cnts) {
    int f = threadIdx.x;   // 128
    int n0 = blockIdx.x * POOL_CHUNK;
    int nend = min(n0 + POOL_CHUNK, NN);
    float acc = 0.f;
    int cnt = 0;
    int gcur = seg[n0];
    for (int n = n0; n < nend; n++) {
        int g = seg[n];
        if (g != gcur) {
            atomicAdd(&hg_sum[gcur * HID + f], acc);
            if (f == 0) atomicAdd(&cnts[gcur], (float)cnt);
            acc = 0.f; cnt = 0; gcur = g;
        }
        acc += h[(size_t)n * HID + f];
        cnt++;
    }
    atomicAdd(&hg_sum[gcur * HID + f], acc);
    if (f == 0) atomicAdd(&cnts[gcur], (float)cnt);
}

__global__ __launch_bounds__(256) void mean_k(const float* __restrict__ hg_sum,
                                              const float* __restrict__ cnts,
                                              float* __restrict__ out) {
    int i = blockIdx.x * 256 + threadIdx.x;   // 16384
    int g = i >> 7;
    out[i] = hg_sum[i] / fmaxf(cnts[g], 1.f);
}

// ---------------- |hg1-hg2| @ Wc + bc ----------------
__global__ __launch_bounds__(128) void logits_k(const float* __restrict__ out_hg,
                                                const float* __restrict__ Wc,
                                                const float* __restrict__ bc,
                                                float* __restrict__ logits) {
    __shared__ float d[HID];
    int g = blockIdx.x;
    int t = threadIdx.x;
    d[t] = fabsf(out_hg[g * HID + t] - out_hg[NG * HID + g * HID + t]);
    __syncthreads();
    if (t < NC) {
        float a = bc[t];
        for (int k = 0; k < HID; k++) a += d[k] * Wc[k * NC + t];
        logits[g * NC + t] = a;
    }
}

extern "C" void kernel_launch(void* const* d_in, const int* in_sizes, int n_in,
                              void* d_out, int out_size, void* d_ws, size_t ws_size,
                              hipStream_t stream) {
    const int* src[2] = { (const int*)d_in[0], (const int*)d_in[3] };
    const int* dst[2] = { (const int*)d_in[1], (const int*)d_in[4] };
    const int* seg[2] = { (const int*)d_in[2], (const int*)d_in[5] };
    const float* W1 = (const float*)d_in[6];
    const float* b1 = (const float*)d_in[7];
    const float* Wl[3] = { (const float*)d_in[8], (const float*)d_in[10], (const float*)d_in[12] };
    const float* bl[3] = { (const float*)d_in[9], (const float*)d_in[11], (const float*)d_in[13] };
    const float* Wc = (const float*)d_in[14];
    const float* bc = (const float*)d_in[15];
    float* out = (float*)d_out;

    // ---- workspace layout (floats) ----
    float* ws = (float*)d_ws;
    float* h  = ws;                       // NN*HID
    float* p  = h + (size_t)NN * HID;     // NN*HID
    int* col       = (int*)(p + (size_t)NN * HID);   // NE
    int* row_start = col + NE;            // NN+1 (+pad)
    int* cursor    = row_start + NN + 2;  // NN
    int* cnt_out   = cursor + NN;         // NN
    int* cnt_in    = cnt_out + NN;        // NN  (contiguous with cnt_out for one memset)
    float* cs   = (float*)(cnt_in + NN);  // NN
    float* cd   = cs + NN;                // NN
    float* s0   = cd + NN;                // NN
    float* aggs = s0 + NN;                // NN
    float* hg_sum = aggs + NN;            // NG*HID
    float* cnts   = hg_sum + NG * HID;    // NG (contiguous with hg_sum for one memset)

    for (int br = 0; br < 2; br++) {
        hipMemsetAsync(cnt_out, 0, 2 * NN * sizeof(int), stream);
        hipMemsetAsync(hg_sum, 0, (NG * HID + NG) * sizeof(float), stream);

        hist_k<<<(NE + 255) / 256, 256, 0, stream>>>(src[br], dst[br], cnt_out, cnt_in);
        scan_k<<<1, 1024, 0, stream>>>(cnt_in, row_start);
        node_prep_k<<<(NN + 255) / 256, 256, 0, stream>>>(cnt_out, cnt_in, row_start, cs, cd, s0, cursor);
        fill_k<<<(NE + 255) / 256, 256, 0, stream>>>(src[br], dst[br], cursor, col);

        // layer 1 (rank-1)
        l1_agg_k<<<(NN + 255) / 256, 256, 0, stream>>>(row_start, col, s0, cd, aggs);
        l1_expand_k<<<(NN * HID) / 256, 256, 0, stream>>>(aggs, W1, b1, h);

        // layers 2..4
        for (int l = 0; l < 3; l++) {
            gemm_k<<<(NN + 63) / 64, 256, 0, stream>>>(h, Wl[l], cs, p);
            agg_relu_k<<<NN / 2, 256, 0, stream>>>(p, row_start, col, cd, bl[l], h);
        }

        // mean pool
        pool_k<<<(NN + POOL_CHUNK - 1) / POOL_CHUNK, 128, 0, stream>>>(h, seg[br], hg_sum, cnts);
        mean_k<<<(NG * HID) / 256, 256, 0, stream>>>(hg_sum, cnts, out + (size_t)br * NG * HID);
    }

    logits_k<<<NG, 128, 0, stream>>>(out, Wc, bc, out + 2 * NG * HID);
}

// Round 2
// 2271.379 us; speedup vs baseline: 1.4530x; 1.4530x over previous
//
#include <hip/hip_runtime.h>

#define NN 100000
#define NE 1600000
#define NG 128
#define HID 128
#define NC 10

typedef unsigned int uint;

// ---------------- histogram of src/dst degrees ----------------
__global__ __launch_bounds__(256) void hist_k(const int* __restrict__ src,
                                              const int* __restrict__ dst,
                                              int* __restrict__ cnt_out,
                                              int* __restrict__ cnt_in) {
    int e = blockIdx.x * 256 + threadIdx.x;
    if (e < NE) {
        atomicAdd(&cnt_out[src[e]], 1);
        atomicAdd(&cnt_in[dst[e]], 1);
    }
}

// ---------------- exclusive scan of in-degree -> row_start ----------------
__global__ __launch_bounds__(1024) void scan_k(const int* __restrict__ cnt,
                                               int* __restrict__ row_start) {
    __shared__ int wsum[16];
    __shared__ int carry;
    int t = threadIdx.x;
    int lane = t & 63, wid = t >> 6;
    int offset = 0;
    for (int base = 0; base < NN; base += 1024) {
        int idx = base + t;
        int v = (idx < NN) ? cnt[idx] : 0;
        int x = v;
#pragma unroll
        for (int d = 1; d < 64; d <<= 1) {
            int y = __shfl_up(x, d, 64);
            if (lane >= d) x += y;
        }
        if (lane == 63) wsum[wid] = x;
        __syncthreads();
        if (t == 0) {
            int s = 0;
#pragma unroll
            for (int i = 0; i < 16; i++) { int tmp = wsum[i]; wsum[i] = s; s += tmp; }
            carry = s;
        }
        __syncthreads();
        int excl = offset + wsum[wid] + (x - v);
        if (idx < NN) row_start[idx] = excl;
        offset += carry;
        __syncthreads();
    }
    if (t == 0) row_start[NN] = offset;
}

// ---------------- per-node: cs, cd, h0*cs, cursor init ----------------
__global__ __launch_bounds__(256) void node_prep_k(const int* __restrict__ cnt_out,
                                                   const int* __restrict__ cnt_in,
                                                   const int* __restrict__ row_start,
                                                   float* __restrict__ cs,
                                                   float* __restrict__ cd,
                                                   float* __restrict__ s0,
                                                   int* __restrict__ cursor) {
    int n = blockIdx.x * 256 + threadIdx.x;
    if (n < NN) {
        float od = (float)cnt_out[n];
        float idg = (float)cnt_in[n];
        float c_s = rsqrtf(fmaxf(od, 1.f));
        float c_d = rsqrtf(fmaxf(idg, 1.f));
        cs[n] = c_s;
        cd[n] = c_d;
        s0[n] = idg * c_s;   // h0 * cs  (h0 = in_deg)
        cursor[n] = row_start[n];
    }
}

// ---------------- CSC fill: group edge srcs by dst ----------------
__global__ __launch_bounds__(256) void fill_k(const int* __restrict__ src,
                                              const int* __restrict__ dst,
                                              int* __restrict__ cursor,
                                              int* __restrict__ col) {
    int e = blockIdx.x * 256 + threadIdx.x;
    if (e < NE) {
        int d = dst[e];
        int pos = atomicAdd(&cursor[d], 1);
        col[pos] = src[e];
    }
}

// ---------------- layer-1 scalar aggregation ----------------
__global__ __launch_bounds__(256) void l1_agg_k(const int* __restrict__ row_start,
                                                const int* __restrict__ col,
                                                const float* __restrict__ s0,
                                                const float* __restrict__ cd,
                                                float* __restrict__ aggs) {
    int n = blockIdx.x * 256 + threadIdx.x;
    if (n < NN) {
        int b = row_start[n], e = row_start[n + 1];
        float a = 0.f;
        for (int i = b; i < e; i++) a += s0[col[i]];
        aggs[n] = a * cd[n];
    }
}

// ---------------- layer-1 rank-1 expand: h = relu(aggs*W1 + b1) ----------------
__global__ __launch_bounds__(256) void l1_expand_k(const float* __restrict__ aggs,
                                                   const float* __restrict__ W1,
                                                   const float* __restrict__ b1,
                                                   float* __restrict__ h) {
    int i = blockIdx.x * 256 + threadIdx.x;   // grid covers NN*HID exactly
    int f = i & (HID - 1);
    int n = i >> 7;
    h[i] = fmaxf(aggs[n] * W1[f] + b1[f], 0.f);
}

// ---------------- bf16 pack (RNE) ----------------
__device__ __forceinline__ uint pack_bf2(float x, float y) {
    uint ux = __float_as_uint(x);
    uint uy = __float_as_uint(y);
    ux = (ux + 0x7fffu + ((ux >> 16) & 1u)) >> 16;
    uy = (uy + 0x7fffu + ((uy >> 16) & 1u)) >> 16;
    return ux | (uy << 16);
}

// ---------------- GEMM: p[n] = bf16( cs[n] * (h[n] @ W) ), fp32 compute ----------------
__global__ __launch_bounds__(256) void gemm_k(const float* __restrict__ h,
                                              const float* __restrict__ W,
                                              const float* __restrict__ cs,
                                              uint* __restrict__ pbf) {
    __shared__ float Wl[HID * HID];   // 64 KB
    int t = threadIdx.x;
    for (int i = t * 4; i < HID * HID; i += 256 * 4) {
        *(float4*)&Wl[i] = *(const float4*)&W[i];
    }
    __syncthreads();

    int n0 = blockIdx.x * 64 + (t >> 5) * 8;
    int c0 = (t & 31) * 4;

    float4 acc[8];
#pragma unroll
    for (int i = 0; i < 8; i++) acc[i] = make_float4(0.f, 0.f, 0.f, 0.f);

    const float* hp[8];
    bool valid[8];
#pragma unroll
    for (int i = 0; i < 8; i++) {
        int n = n0 + i;
        valid[i] = (n < NN);
        hp[i] = h + (size_t)(valid[i] ? n : 0) * HID;
    }

    for (int k = 0; k < HID; k += 4) {
        float4 w0 = *(float4*)&Wl[(k + 0) * HID + c0];
        float4 w1 = *(float4*)&Wl[(k + 1) * HID + c0];
        float4 w2 = *(float4*)&Wl[(k + 2) * HID + c0];
        float4 w3 = *(float4*)&Wl[(k + 3) * HID + c0];
#pragma unroll
        for (int i = 0; i < 8; i++) {
            float4 a = *(const float4*)(hp[i] + k);
            acc[i].x += a.x * w0.x + a.y * w1.x + a.z * w2.x + a.w * w3.x;
            acc[i].y += a.x * w0.y + a.y * w1.y + a.z * w2.y + a.w * w3.y;
            acc[i].z += a.x * w0.z + a.y * w1.z + a.z * w2.z + a.w * w3.z;
            acc[i].w += a.x * w0.w + a.y * w1.w + a.z * w2.w + a.w * w3.w;
        }
    }

#pragma unroll
    for (int i = 0; i < 8; i++) {
        int n = n0 + i;
        if (valid[i]) {
            float s = cs[n];
            float4 r = acc[i];
            uint2 w;
            w.x = pack_bf2(r.x * s, r.y * s);
            w.y = pack_bf2(r.z * s, r.w * s);
            *(uint2*)&pbf[(size_t)n * (HID / 2) + (t & 31) * 2] = w;
        }
    }
}

// ---------------- aggregate bf16 p over incoming edges, relu epilogue ----------------
// one wave per node; lane covers features (2*lane, 2*lane+1) via packed uint load
__global__ __launch_bounds__(256) void agg_relu_k(const uint* __restrict__ pbf,
                                                  const int* __restrict__ row_start,
                                                  const int* __restrict__ col,
                                                  const float* __restrict__ cd,
                                                  const float* __restrict__ b,
                                                  float* __restrict__ h) {
    int t = threadIdx.x;
    int lane = t & 63;
    int n = blockIdx.x * 4 + (t >> 6);
    int beg = row_start[n], end = row_start[n + 1];
    float ax = 0.f, ay = 0.f;
    for (int i = beg; i < end; i++) {
        int c = col[i];
        uint v = pbf[(size_t)c * (HID / 2) + lane];
        ax += __uint_as_float(v << 16);
        ay += __uint_as_float(v & 0xffff0000u);
    }
    float s = cd[n];
    int f = lane * 2;
    float2 r;
    r.x = fmaxf(ax * s + b[f], 0.f);
    r.y = fmaxf(ay * s + b[f + 1], 0.f);
    *(float2*)&h[(size_t)n * HID + f] = r;
}

// ---------------- mean-pool per graph (seg sorted -> contiguous ranges) ----------------
__device__ __forceinline__ int lower_bound_seg(const int* __restrict__ seg, int val) {
    int lo = 0, hi = NN;
    while (lo < hi) {
        int m = (lo + hi) >> 1;
        if (seg[m] < val) lo = m + 1; else hi = m;
    }
    return lo;
}

__global__ __launch_bounds__(1024) void pool_k(const float* __restrict__ h,
                                               const int* __restrict__ seg,
                                               float* __restrict__ out) {
    __shared__ int sb[2];
    __shared__ float buf[8 * HID];
    int g = blockIdx.x;
    int t = threadIdx.x;
    if (t < 2) sb[t] = lower_bound_seg(seg, g + t);
    __syncthreads();
    int beg = sb[0], end = sb[1];
    int f = t & (HID - 1), part = t >> 7;
    float acc = 0.f;
    for (int n = beg + part; n < end; n += 8) acc += h[(size_t)n * HID + f];
    buf[part * HID + f] = acc;
    __syncthreads();
    if (part == 0) {
        float s = acc;
#pragma unroll
        for (int i = 1; i < 8; i++) s += buf[i * HID + f];
        out[g * HID + f] = s / fmaxf((float)(end - beg), 1.f);
    }
}

// ---------------- |hg1-hg2| @ Wc + bc ----------------
__global__ __launch_bounds__(128) void logits_k(const float* __restrict__ out_hg,
                                                const float* __restrict__ Wc,
                                                const float* __restrict__ bc,
                                                float* __restrict__ logits) {
    __shared__ float d[HID];
    int g = blockIdx.x;
    int t = threadIdx.x;
    d[t] = fabsf(out_hg[g * HID + t] - out_hg[NG * HID + g * HID + t]);
    __syncthreads();
    if (t < NC) {
        float a = bc[t];
        for (int k = 0; k < HID; k++) a += d[k] * Wc[k * NC + t];
        logits[g * NC + t] = a;
    }
}

extern "C" void kernel_launch(void* const* d_in, const int* in_sizes, int n_in,
                              void* d_out, int out_size, void* d_ws, size_t ws_size,
                              hipStream_t stream) {
    const int* src[2] = { (const int*)d_in[0], (const int*)d_in[3] };
    const int* dst[2] = { (const int*)d_in[1], (const int*)d_in[4] };
    const int* seg[2] = { (const int*)d_in[2], (const int*)d_in[5] };
    const float* W1 = (const float*)d_in[6];
    const float* b1 = (const float*)d_in[7];
    const float* Wl[3] = { (const float*)d_in[8], (const float*)d_in[10], (const float*)d_in[12] };
    const float* bl[3] = { (const float*)d_in[9], (const float*)d_in[11], (const float*)d_in[13] };
    const float* Wc = (const float*)d_in[14];
    const float* bc = (const float*)d_in[15];
    float* out = (float*)d_out;

    // ---- workspace layout ----
    float* ws = (float*)d_ws;
    float* h  = ws;                              // NN*HID fp32
    uint* pbf = (uint*)(h + (size_t)NN * HID);   // NN*HID/2 uints (bf16x2)
    int* col       = (int*)(pbf + (size_t)NN * (HID / 2));  // NE
    int* row_start = col + NE;            // NN+1 (+pad)
    int* cursor    = row_start + NN + 2;  // NN
    int* cnt_out   = cursor + NN;         // NN
    int* cnt_in    = cnt_out + NN;        // NN  (contiguous with cnt_out for one memset)
    float* cs   = (float*)(cnt_in + NN);  // NN
    float* cd   = cs + NN;                // NN
    float* s0   = cd + NN;                // NN
    float* aggs = s0 + NN;                // NN

    for (int br = 0; br < 2; br++) {
        hipMemsetAsync(cnt_out, 0, 2 * NN * sizeof(int), stream);

        hist_k<<<(NE + 255) / 256, 256, 0, stream>>>(src[br], dst[br], cnt_out, cnt_in);
        scan_k<<<1, 1024, 0, stream>>>(cnt_in, row_start);
        node_prep_k<<<(NN + 255) / 256, 256, 0, stream>>>(cnt_out, cnt_in, row_start, cs, cd, s0, cursor);
        fill_k<<<(NE + 255) / 256, 256, 0, stream>>>(src[br], dst[br], cursor, col);

        // layer 1 (rank-1)
        l1_agg_k<<<(NN + 255) / 256, 256, 0, stream>>>(row_start, col, s0, cd, aggs);
        l1_expand_k<<<(NN * HID) / 256, 256, 0, stream>>>(aggs, W1, b1, h);

        // layers 2..4
        for (int l = 0; l < 3; l++) {
            gemm_k<<<(NN + 63) / 64, 256, 0, stream>>>(h, Wl[l], cs, pbf);
            agg_relu_k<<<NN / 4, 256, 0, stream>>>(pbf, row_start, col, cd, bl[l], h);
        }

        // mean pool (fused mean, no atomics)
        pool_k<<<NG, 1024, 0, stream>>>(h, seg[br], out + (size_t)br * NG * HID);
    }

    logits_k<<<NG, 128, 0, stream>>>(out, Wc, bc, out + 2 * NG * HID);
}

// Round 3
// 1414.781 us; speedup vs baseline: 2.3328x; 1.6055x over previous
//
#include <hip/hip_runtime.h>

#define NN 100000
#define NE 1600000
#define NT (2 * NN)
#define ET (2 * NE)
#define NG 128
#define HID 128
#define NC 10
#define SCAN_NB ((NT + 1023) / 1024)   // 196

typedef unsigned int uint;

__device__ __forceinline__ float bf_lo(uint v) { return __uint_as_float(v << 16); }
__device__ __forceinline__ float bf_hi(uint v) { return __uint_as_float(v & 0xffff0000u); }
__device__ __forceinline__ uint pack_bf2(float x, float y) {
    uint ux = __float_as_uint(x);
    uint uy = __float_as_uint(y);
    ux = (ux + 0x7fffu + ((ux >> 16) & 1u)) >> 16;
    uy = (uy + 0x7fffu + ((uy >> 16) & 1u)) >> 16;
    return ux | (uy << 16);
}

// ---------------- degree histograms, both branches ----------------
__global__ __launch_bounds__(256) void hist_k(const int* __restrict__ src1, const int* __restrict__ dst1,
                                              const int* __restrict__ src2, const int* __restrict__ dst2,
                                              int* __restrict__ cnt_out, int* __restrict__ cnt_in) {
    int e = blockIdx.x * 256 + threadIdx.x;          // 0 .. ET
    int br = (e >= NE);                               // block-uniform (NE % 256 == 0)
    int ee = br ? e - NE : e;
    int s = br ? src2[ee] + NN : src1[ee];
    int d = br ? dst2[ee] + NN : dst1[ee];
    atomicAdd(&cnt_out[s], 1);
    atomicAdd(&cnt_in[d], 1);
}

// ---------------- 3-kernel exclusive scan of cnt_in -> row_start ----------------
__global__ __launch_bounds__(1024) void scan_reduce_k(const int* __restrict__ cnt, int* __restrict__ bsum) {
    __shared__ int ws[16];
    int t = threadIdx.x;
    int idx = blockIdx.x * 1024 + t;
    int v = (idx < NT) ? cnt[idx] : 0;
#pragma unroll
    for (int d = 1; d < 64; d <<= 1) v += __shfl_xor(v, d, 64);
    if ((t & 63) == 0) ws[t >> 6] = v;
    __syncthreads();
    if (t == 0) {
        int s = 0;
#pragma unroll
        for (int i = 0; i < 16; i++) s += ws[i];
        bsum[blockIdx.x] = s;
    }
}

__global__ __launch_bounds__(256) void scan_partials_k(const int* __restrict__ bsum,
                                                       int* __restrict__ boff,
                                                       int* __restrict__ row_start) {
    __shared__ int ws[4];
    int t = threadIdx.x;
    int lane = t & 63, wid = t >> 6;
    int v = (t < SCAN_NB) ? bsum[t] : 0;
    int x = v;
#pragma unroll
    for (int d = 1; d < 64; d <<= 1) { int y = __shfl_up(x, d, 64); if (lane >= d) x += y; }
    if (lane == 63) ws[wid] = x;
    __syncthreads();
    int off = 0;
    for (int i = 0; i < wid; i++) off += ws[i];
    if (t < SCAN_NB) boff[t] = off + x - v;
    if (t == 0) row_start[NT] = ET;
}

__global__ __launch_bounds__(1024) void scan_final_k(const int* __restrict__ cnt,
                                                     const int* __restrict__ boff,
                                                     int* __restrict__ row_start) {
    __shared__ int ws[16];
    int t = threadIdx.x;
    int lane = t & 63, wid = t >> 6;
    int idx = blockIdx.x * 1024 + t;
    int v = (idx < NT) ? cnt[idx] : 0;
    int x = v;
#pragma unroll
    for (int d = 1; d < 64; d <<= 1) { int y = __shfl_up(x, d, 64); if (lane >= d) x += y; }
    if (lane == 63) ws[wid] = x;
    __syncthreads();
    if (t == 0) {
        int s = 0;
#pragma unroll
        for (int i = 0; i < 16; i++) { int tmp = ws[i]; ws[i] = s; s += tmp; }
    }
    __syncthreads();
    if (idx < NT) row_start[idx] = boff[blockIdx.x] + ws[wid] + (x - v);
}

// ---------------- per-node: cs, cd, h0*cs, cursor init ----------------
__global__ __launch_bounds__(256) void node_prep_k(const int* __restrict__ cnt_out,
                                                   const int* __restrict__ cnt_in,
                                                   const int* __restrict__ row_start,
                                                   float* __restrict__ cs, float* __restrict__ cd,
                                                   float* __restrict__ s0, int* __restrict__ cursor) {
    int n = blockIdx.x * 256 + threadIdx.x;
    if (n < NT) {
        float od = (float)cnt_out[n];
        float idg = (float)cnt_in[n];
        float c_s = rsqrtf(fmaxf(od, 1.f));
        cs[n] = c_s;
        cd[n] = rsqrtf(fmaxf(idg, 1.f));
        s0[n] = idg * c_s;
        cursor[n] = row_start[n];
    }
}

// ---------------- CSC fill, both branches ----------------
__global__ __launch_bounds__(256) void fill_k(const int* __restrict__ src1, const int* __restrict__ dst1,
                                              const int* __restrict__ src2, const int* __restrict__ dst2,
                                              int* __restrict__ cursor, int* __restrict__ col) {
    int e = blockIdx.x * 256 + threadIdx.x;
    int br = (e >= NE);
    int ee = br ? e - NE : e;
    int s = br ? src2[ee] + NN : src1[ee];
    int d = br ? dst2[ee] + NN : dst1[ee];
    int pos = atomicAdd(&cursor[d], 1);
    col[pos] = s;
}

// ---------------- layer-1 scalar aggregation ----------------
__global__ __launch_bounds__(256) void l1_agg_k(const int* __restrict__ row_start, const int* __restrict__ col,
                                                const float* __restrict__ s0, const float* __restrict__ cd,
                                                float* __restrict__ aggs) {
    int n = blockIdx.x * 256 + threadIdx.x;
    if (n < NT) {
        int b = row_start[n], e = row_start[n + 1];
        float a = 0.f;
        for (int i = b; i < e; i++) a += s0[col[i]];
        aggs[n] = a * cd[n];
    }
}

// ---------------- layer-1 rank-1 expand -> packed bf16 h ----------------
__global__ __launch_bounds__(256) void l1_expand_k(const float* __restrict__ aggs,
                                                   const float* __restrict__ W1, const float* __restrict__ b1,
                                                   uint* __restrict__ hbf) {
    int i = blockIdx.x * 256 + threadIdx.x;   // NT*64 exact
    int u = i & 63;
    int n = i >> 6;
    float a = aggs[n];
    float v0 = fmaxf(a * W1[2 * u] + b1[2 * u], 0.f);
    float v1 = fmaxf(a * W1[2 * u + 1] + b1[2 * u + 1], 0.f);
    hbf[i] = pack_bf2(v0, v1);
}

// ---------------- GEMM: pbf[n] = bf16( cs[n] * (h[n] @ W) ), fp32 compute ----------------
__global__ __launch_bounds__(256) void gemm_k(const uint* __restrict__ hbf, const float* __restrict__ W,
                                              const float* __restrict__ cs, uint* __restrict__ pbf) {
    __shared__ float Wl[HID * HID];   // 64 KB
    int t = threadIdx.x;
    for (int i = t * 4; i < HID * HID; i += 256 * 4) {
        *(float4*)&Wl[i] = *(const float4*)&W[i];
    }
    __syncthreads();

    int n0 = blockIdx.x * 64 + (t >> 5) * 8;   // NT % 64 == 0, no guards
    int c0 = (t & 31) * 4;

    float4 acc[8];
#pragma unroll
    for (int i = 0; i < 8; i++) acc[i] = make_float4(0.f, 0.f, 0.f, 0.f);

    const uint* hp[8];
#pragma unroll
    for (int i = 0; i < 8; i++) hp[i] = hbf + (size_t)(n0 + i) * 64;

    for (int k = 0; k < HID; k += 4) {
        float4 w0 = *(float4*)&Wl[(k + 0) * HID + c0];
        float4 w1 = *(float4*)&Wl[(k + 1) * HID + c0];
        float4 w2 = *(float4*)&Wl[(k + 2) * HID + c0];
        float4 w3 = *(float4*)&Wl[(k + 3) * HID + c0];
#pragma unroll
        for (int i = 0; i < 8; i++) {
            uint2 a2 = *(const uint2*)(hp[i] + (k >> 1));
            float a0 = bf_lo(a2.x), a1 = bf_hi(a2.x), a2f = bf_lo(a2.y), a3 = bf_hi(a2.y);
            acc[i].x += a0 * w0.x + a1 * w1.x + a2f * w2.x + a3 * w3.x;
            acc[i].y += a0 * w0.y + a1 * w1.y + a2f * w2.y + a3 * w3.y;
            acc[i].z += a0 * w0.z + a1 * w1.z + a2f * w2.z + a3 * w3.z;
            acc[i].w += a0 * w0.w + a1 * w1.w + a2f * w2.w + a3 * w3.w;
        }
    }

#pragma unroll
    for (int i = 0; i < 8; i++) {
        int n = n0 + i;
        float s = cs[n];
        uint2 w;
        w.x = pack_bf2(acc[i].x * s, acc[i].y * s);
        w.y = pack_bf2(acc[i].z * s, acc[i].w * s);
        *(uint2*)&pbf[(size_t)n * 64 + (t & 31) * 2] = w;
    }
}

// ---------------- aggregate bf16 p over incoming edges, relu, write bf16 h ----------------
// one wave per node, 4-way unrolled independent gathers for MLP
__global__ __launch_bounds__(256) void agg_relu_k(const uint* __restrict__ pbf,
                                                  const int* __restrict__ row_start,
                                                  const int* __restrict__ col,
                                                  const float* __restrict__ cd,
                                                  const float* __restrict__ b,
                                                  uint* __restrict__ hbf) {
    int t = threadIdx.x;
    int lane = t & 63;
    int n = blockIdx.x * 4 + (t >> 6);
    int beg = __builtin_amdgcn_readfirstlane(row_start[n]);
    int end = __builtin_amdgcn_readfirstlane(row_start[n + 1]);
    float ax = 0.f, ay = 0.f;
    int i = beg;
    for (; i + 4 <= end; i += 4) {
        int c0 = col[i], c1 = col[i + 1], c2 = col[i + 2], c3 = col[i + 3];
        uint v0 = pbf[(size_t)c0 * 64 + lane];
        uint v1 = pbf[(size_t)c1 * 64 + lane];
        uint v2 = pbf[(size_t)c2 * 64 + lane];
        uint v3 = pbf[(size_t)c3 * 64 + lane];
        ax += bf_lo(v0) + bf_lo(v1) + bf_lo(v2) + bf_lo(v3);
        ay += bf_hi(v0) + bf_hi(v1) + bf_hi(v2) + bf_hi(v3);
    }
    for (; i < end; i++) {
        uint v = pbf[(size_t)col[i] * 64 + lane];
        ax += bf_lo(v);
        ay += bf_hi(v);
    }
    float s = cd[n];
    float r0 = fmaxf(ax * s + b[2 * lane], 0.f);
    float r1 = fmaxf(ay * s + b[2 * lane + 1], 0.f);
    hbf[(size_t)n * 64 + lane] = pack_bf2(r0, r1);
}

// ---------------- mean-pool per graph (seg sorted -> contiguous ranges) ----------------
__device__ __forceinline__ int lower_bound_seg(const int* __restrict__ seg, int val) {
    int lo = 0, hi = NN;
    while (lo < hi) {
        int m = (lo + hi) >> 1;
        if (seg[m] < val) lo = m + 1; else hi = m;
    }
    return lo;
}

__global__ __launch_bounds__(1024) void pool_k(const uint* __restrict__ hbf,
                                               const int* __restrict__ seg1, const int* __restrict__ seg2,
                                               float* __restrict__ out) {
    __shared__ int sb[2];
    __shared__ float2 buf[16 * 64];
    int g = blockIdx.x;            // 0..255
    int br = g >> 7;
    int gg = g & 127;
    const int* seg = br ? seg2 : seg1;
    int t = threadIdx.x;
    if (t < 2) sb[t] = lower_bound_seg(seg, gg + t);
    __syncthreads();
    int beg = sb[0], end = sb[1];
    int u = t & 63, part = t >> 6;   // 16 parts
    size_t base = (size_t)br * NN;
    float ax = 0.f, ay = 0.f;
    for (int n = beg + part; n < end; n += 16) {
        uint v = hbf[(base + n) * 64 + u];
        ax += bf_lo(v);
        ay += bf_hi(v);
    }
    buf[part * 64 + u] = make_float2(ax, ay);
    __syncthreads();
    if (part == 0) {
        float2 s = buf[u];
#pragma unroll
        for (int i = 1; i < 16; i++) { s.x += buf[i * 64 + u].x; s.y += buf[i * 64 + u].y; }
        float inv = 1.f / fmaxf((float)(end - beg), 1.f);
        out[g * HID + 2 * u] = s.x * inv;
        out[g * HID + 2 * u + 1] = s.y * inv;
    }
}

// ---------------- |hg1-hg2| @ Wc + bc ----------------
__global__ __launch_bounds__(128) void logits_k(const float* __restrict__ out_hg,
                                                const float* __restrict__ Wc,
                                                const float* __restrict__ bc,
                                                float* __restrict__ logits) {
    __shared__ float d[HID];
    int g = blockIdx.x;
    int t = threadIdx.x;
    d[t] = fabsf(out_hg[g * HID + t] - out_hg[NG * HID + g * HID + t]);
    __syncthreads();
    if (t < NC) {
        float a = bc[t];
        for (int k = 0; k < HID; k++) a += d[k] * Wc[k * NC + t];
        logits[g * NC + t] = a;
    }
}

extern "C" void kernel_launch(void* const* d_in, const int* in_sizes, int n_in,
                              void* d_out, int out_size, void* d_ws, size_t ws_size,
                              hipStream_t stream) {
    const int* src1 = (const int*)d_in[0];
    const int* dst1 = (const int*)d_in[1];
    const int* seg1 = (const int*)d_in[2];
    const int* src2 = (const int*)d_in[3];
    const int* dst2 = (const int*)d_in[4];
    const int* seg2 = (const int*)d_in[5];
    const float* W1 = (const float*)d_in[6];
    const float* b1 = (const float*)d_in[7];
    const float* Wl[3] = { (const float*)d_in[8], (const float*)d_in[10], (const float*)d_in[12] };
    const float* bl[3] = { (const float*)d_in[9], (const float*)d_in[11], (const float*)d_in[13] };
    const float* Wc = (const float*)d_in[14];
    const float* bc = (const float*)d_in[15];
    float* out = (float*)d_out;

    // ---- workspace layout ----
    uint* hbf = (uint*)d_ws;                        // NT*64 (bf16x2 packed h)
    uint* pbf = hbf + (size_t)NT * 64;              // NT*64 (bf16x2 packed p)
    int* col       = (int*)(pbf + (size_t)NT * 64); // ET
    int* row_start = col + ET;                      // NT+1
    int* cursor    = row_start + NT + 2;            // NT
    int* cnt_out   = cursor + NT;                   // NT
    int* cnt_in    = cnt_out + NT;                  // NT (contiguous with cnt_out)
    float* cs   = (float*)(cnt_in + NT);            // NT
    float* cd   = cs + NT;                          // NT
    float* s0   = cd + NT;                          // NT
    float* aggs = s0 + NT;                          // NT
    int* bsum   = (int*)(aggs + NT);                // SCAN_NB
    int* boff   = bsum + SCAN_NB;                   // SCAN_NB

    hipMemsetAsync(cnt_out, 0, 2 * NT * sizeof(int), stream);

    hist_k<<<ET / 256, 256, 0, stream>>>(src1, dst1, src2, dst2, cnt_out, cnt_in);
    scan_reduce_k<<<SCAN_NB, 1024, 0, stream>>>(cnt_in, bsum);
    scan_partials_k<<<1, 256, 0, stream>>>(bsum, boff, row_start);
    scan_final_k<<<SCAN_NB, 1024, 0, stream>>>(cnt_in, boff, row_start);
    node_prep_k<<<(NT + 255) / 256, 256, 0, stream>>>(cnt_out, cnt_in, row_start, cs, cd, s0, cursor);
    fill_k<<<ET / 256, 256, 0, stream>>>(src1, dst1, src2, dst2, cursor, col);

    // layer 1 (rank-1)
    l1_agg_k<<<(NT + 255) / 256, 256, 0, stream>>>(row_start, col, s0, cd, aggs);
    l1_expand_k<<<(NT * 64) / 256, 256, 0, stream>>>(aggs, W1, b1, hbf);

    // layers 2..4
    for (int l = 0; l < 3; l++) {
        gemm_k<<<NT / 64, 256, 0, stream>>>(hbf, Wl[l], cs, pbf);
        agg_relu_k<<<NT / 4, 256, 0, stream>>>(pbf, row_start, col, cd, bl[l], hbf);
    }

    // mean pool (both branches), writes hg1|hg2 directly
    pool_k<<<2 * NG, 1024, 0, stream>>>(hbf, seg1, seg2, out);

    logits_k<<<NG, 128, 0, stream>>>(out, Wc, bc, out + 2 * NG * HID);
}

// Round 4
// 1177.209 us; speedup vs baseline: 2.8036x; 1.2018x over previous
//
#include <hip/hip_runtime.h>

#define NN 100000
#define NE 1600000
#define NT (2 * NN)
#define ET (2 * NE)
#define NG 128
#define HID 128
#define NC 10
#define SCAN_NB ((NT + 1023) / 1024)   // 196

typedef unsigned int uint;
typedef __attribute__((ext_vector_type(8))) short bf16x8;
typedef __attribute__((ext_vector_type(4))) float f32x4;

union U8 { uint4 u; bf16x8 v; };

__device__ __forceinline__ float bf_lo(uint v) { return __uint_as_float(v << 16); }
__device__ __forceinline__ float bf_hi(uint v) { return __uint_as_float(v & 0xffff0000u); }
__device__ __forceinline__ uint bf_round16(float x) {   // 16-bit bf16 value (RNE)
    uint ux = __float_as_uint(x);
    return (ux + 0x7fffu + ((ux >> 16) & 1u)) >> 16;
}
__device__ __forceinline__ uint pack_bf2(float x, float y) {
    return bf_round16(x) | (bf_round16(y) << 16);
}

// ---------------- degree histograms, both branches ----------------
__global__ __launch_bounds__(256) void hist_k(const int* __restrict__ src1, const int* __restrict__ dst1,
                                              const int* __restrict__ src2, const int* __restrict__ dst2,
                                              int* __restrict__ cnt_out, int* __restrict__ cnt_in) {
    int e = blockIdx.x * 256 + threadIdx.x;          // 0 .. ET
    int br = (e >= NE);                               // block-uniform (NE % 256 == 0)
    int ee = br ? e - NE : e;
    int s = br ? src2[ee] + NN : src1[ee];
    int d = br ? dst2[ee] + NN : dst1[ee];
    atomicAdd(&cnt_out[s], 1);
    atomicAdd(&cnt_in[d], 1);
}

// ---------------- 3-kernel exclusive scan of cnt_in -> row_start ----------------
__global__ __launch_bounds__(1024) void scan_reduce_k(const int* __restrict__ cnt, int* __restrict__ bsum) {
    __shared__ int ws[16];
    int t = threadIdx.x;
    int idx = blockIdx.x * 1024 + t;
    int v = (idx < NT) ? cnt[idx] : 0;
#pragma unroll
    for (int d = 1; d < 64; d <<= 1) v += __shfl_xor(v, d, 64);
    if ((t & 63) == 0) ws[t >> 6] = v;
    __syncthreads();
    if (t == 0) {
        int s = 0;
#pragma unroll
        for (int i = 0; i < 16; i++) s += ws[i];
        bsum[blockIdx.x] = s;
    }
}

__global__ __launch_bounds__(256) void scan_partials_k(const int* __restrict__ bsum,
                                                       int* __restrict__ boff,
                                                       int* __restrict__ row_start) {
    __shared__ int ws[4];
    int t = threadIdx.x;
    int lane = t & 63, wid = t >> 6;
    int v = (t < SCAN_NB) ? bsum[t] : 0;
    int x = v;
#pragma unroll
    for (int d = 1; d < 64; d <<= 1) { int y = __shfl_up(x, d, 64); if (lane >= d) x += y; }
    if (lane == 63) ws[wid] = x;
    __syncthreads();
    int off = 0;
    for (int i = 0; i < wid; i++) off += ws[i];
    if (t < SCAN_NB) boff[t] = off + x - v;
    if (t == 0) row_start[NT] = ET;
}

__global__ __launch_bounds__(1024) void scan_final_k(const int* __restrict__ cnt,
                                                     const int* __restrict__ boff,
                                                     int* __restrict__ row_start) {
    __shared__ int ws[16];
    int t = threadIdx.x;
    int lane = t & 63, wid = t >> 6;
    int idx = blockIdx.x * 1024 + t;
    int v = (idx < NT) ? cnt[idx] : 0;
    int x = v;
#pragma unroll
    for (int d = 1; d < 64; d <<= 1) { int y = __shfl_up(x, d, 64); if (lane >= d) x += y; }
    if (lane == 63) ws[wid] = x;
    __syncthreads();
    if (t == 0) {
        int s = 0;
#pragma unroll
        for (int i = 0; i < 16; i++) { int tmp = ws[i]; ws[i] = s; s += tmp; }
    }
    __syncthreads();
    if (idx < NT) row_start[idx] = boff[blockIdx.x] + ws[wid] + (x - v);
}

// ---------------- per-node: cs, cd, h0*cs, cursor init ----------------
__global__ __launch_bounds__(256) void node_prep_k(const int* __restrict__ cnt_out,
                                                   const int* __restrict__ cnt_in,
                                                   const int* __restrict__ row_start,
                                                   float* __restrict__ cs, float* __restrict__ cd,
                                                   float* __restrict__ s0, int* __restrict__ cursor) {
    int n = blockIdx.x * 256 + threadIdx.x;
    if (n < NT) {
        float od = (float)cnt_out[n];
        float idg = (float)cnt_in[n];
        float c_s = rsqrtf(fmaxf(od, 1.f));
        cs[n] = c_s;
        cd[n] = rsqrtf(fmaxf(idg, 1.f));
        s0[n] = idg * c_s;
        cursor[n] = row_start[n];
    }
}

// ---------------- CSC fill, both branches ----------------
__global__ __launch_bounds__(256) void fill_k(const int* __restrict__ src1, const int* __restrict__ dst1,
                                              const int* __restrict__ src2, const int* __restrict__ dst2,
                                              int* __restrict__ cursor, int* __restrict__ col) {
    int e = blockIdx.x * 256 + threadIdx.x;
    int br = (e >= NE);
    int ee = br ? e - NE : e;
    int s = br ? src2[ee] + NN : src1[ee];
    int d = br ? dst2[ee] + NN : dst1[ee];
    int pos = atomicAdd(&cursor[d], 1);
    col[pos] = s;
}

// ---------------- layer-1 scalar aggregation ----------------
__global__ __launch_bounds__(256) void l1_agg_k(const int* __restrict__ row_start, const int* __restrict__ col,
                                                const float* __restrict__ s0, const float* __restrict__ cd,
                                                float* __restrict__ aggs) {
    int n = blockIdx.x * 256 + threadIdx.x;
    if (n < NT) {
        int b = row_start[n], e = row_start[n + 1];
        float a = 0.f;
        for (int i = b; i < e; i++) a += s0[col[i]];
        aggs[n] = a * cd[n];
    }
}

// ---------------- layer-1 rank-1 expand -> packed bf16 h ----------------
__global__ __launch_bounds__(256) void l1_expand_k(const float* __restrict__ aggs,
                                                   const float* __restrict__ W1, const float* __restrict__ b1,
                                                   uint* __restrict__ hbf) {
    int i = blockIdx.x * 256 + threadIdx.x;   // NT*64 exact
    int u = i & 63;
    int n = i >> 6;
    float a = aggs[n];
    float v0 = fmaxf(a * W1[2 * u] + b1[2 * u], 0.f);
    float v1 = fmaxf(a * W1[2 * u + 1] + b1[2 * u + 1], 0.f);
    hbf[i] = pack_bf2(v0, v1);
}

// ---------------- MFMA GEMM: pbf[n] = bf16( cs[n] * (h[n] @ W) ) ----------------
// 64 rows/block (16/wave), N=128 full width, K=128.
// W split into bf16 hi+lo planes staged in LDS in B-fragment layout, so the
// result is fp32-accurate despite bf16 MFMA inputs.
// B-frag layout (16x16x32): col = lane&15, k = (lane>>4)*8 + j  (j=0..7)
// A-frag layout:            row = lane&15, k = (lane>>4)*8 + j
// C/D layout:               col = lane&15, row = (lane>>4)*4 + reg
__global__ __launch_bounds__(256) void gemm_k(const uint* __restrict__ hbf, const float* __restrict__ W,
                                              const float* __restrict__ cs, uint* __restrict__ pbf) {
    __shared__ uint4 Bh[32 * 64];   // 32 KB: set s = ks*8+n0, per set 64 lanes x uint4
    __shared__ uint4 Bl[32 * 64];   // 32 KB: lo-plane
    int t = threadIdx.x;
    int lane = t & 63;

    // stage W -> B-frag hi/lo planes
    for (int s = t >> 6; s < 32; s += 4) {
        int ks = s >> 3, n0 = s & 7;
        int k0 = ks * 32 + (lane >> 4) * 8;
        int c = n0 * 16 + (lane & 15);
        uint4 hv, lv;
        uint* hp = (uint*)&hv;
        uint* lp = (uint*)&lv;
#pragma unroll
        for (int g = 0; g < 4; g++) {
            float w0 = W[(k0 + 2 * g) * HID + c];
            float w1 = W[(k0 + 2 * g + 1) * HID + c];
            uint h0 = bf_round16(w0), h1 = bf_round16(w1);
            float r0 = w0 - __uint_as_float(h0 << 16);
            float r1 = w1 - __uint_as_float(h1 << 16);
            hp[g] = h0 | (h1 << 16);
            lp[g] = pack_bf2(r0, r1);
        }
        Bh[s * 64 + lane] = hv;
        Bl[s * 64 + lane] = lv;
    }
    __syncthreads();

    int wv = t >> 6;
    int m0w = blockIdx.x * 64 + wv * 16;           // NT % 64 == 0
    int row = m0w + (lane & 15);
    int quad = lane >> 4;

    // A fragments straight from global packed bf16 h
    U8 a[4];
#pragma unroll
    for (int ks = 0; ks < 4; ks++)
        a[ks].u = *(const uint4*)&hbf[(size_t)row * 64 + ks * 16 + quad * 4];

    f32x4 acc[8];
#pragma unroll
    for (int i = 0; i < 8; i++) acc[i] = (f32x4)(0.f);

#pragma unroll
    for (int ks = 0; ks < 4; ks++) {
#pragma unroll
        for (int n0 = 0; n0 < 8; n0++) {
            U8 b;
            b.u = Bh[(ks * 8 + n0) * 64 + lane];
            acc[n0] = __builtin_amdgcn_mfma_f32_16x16x32_bf16(a[ks].v, b.v, acc[n0], 0, 0, 0);
        }
#pragma unroll
        for (int n0 = 0; n0 < 8; n0++) {
            U8 b;
            b.u = Bl[(ks * 8 + n0) * 64 + lane];
            acc[n0] = __builtin_amdgcn_mfma_f32_16x16x32_bf16(a[ks].v, b.v, acc[n0], 0, 0, 0);
        }
    }

    // epilogue: scale by cs[row], pack col-pairs via shfl, store bf16x2
    float4 cs4 = *(const float4*)&cs[m0w + quad * 4];
    const float csr[4] = { cs4.x, cs4.y, cs4.z, cs4.w };
#pragma unroll
    for (int n0 = 0; n0 < 8; n0++) {
#pragma unroll
        for (int r = 0; r < 4; r++) {
            float v = acc[n0][r] * csr[r];
            float partner = __shfl_xor(v, 1, 64);
            if (!(lane & 1)) {
                int rg = m0w + quad * 4 + r;
                pbf[(size_t)rg * 64 + n0 * 8 + ((lane & 15) >> 1)] = pack_bf2(v, partner);
            }
        }
    }
}

// ---------------- aggregate bf16 p over incoming edges, relu, write bf16 h ----------------
__global__ __launch_bounds__(256) void agg_relu_k(const uint* __restrict__ pbf,
                                                  const int* __restrict__ row_start,
                                                  const int* __restrict__ col,
                                                  const float* __restrict__ cd,
                                                  const float* __restrict__ b,
                                                  uint* __restrict__ hbf) {
    int t = threadIdx.x;
    int lane = t & 63;
    int n = blockIdx.x * 4 + (t >> 6);
    int beg = __builtin_amdgcn_readfirstlane(row_start[n]);
    int end = __builtin_amdgcn_readfirstlane(row_start[n + 1]);
    float ax = 0.f, ay = 0.f;
    int i = beg;
    for (; i + 4 <= end; i += 4) {
        int c0 = col[i], c1 = col[i + 1], c2 = col[i + 2], c3 = col[i + 3];
        uint v0 = pbf[(size_t)c0 * 64 + lane];
        uint v1 = pbf[(size_t)c1 * 64 + lane];
        uint v2 = pbf[(size_t)c2 * 64 + lane];
        uint v3 = pbf[(size_t)c3 * 64 + lane];
        ax += bf_lo(v0) + bf_lo(v1) + bf_lo(v2) + bf_lo(v3);
        ay += bf_hi(v0) + bf_hi(v1) + bf_hi(v2) + bf_hi(v3);
    }
    for (; i < end; i++) {
        uint v = pbf[(size_t)col[i] * 64 + lane];
        ax += bf_lo(v);
        ay += bf_hi(v);
    }
    float s = cd[n];
    float r0 = fmaxf(ax * s + b[2 * lane], 0.f);
    float r1 = fmaxf(ay * s + b[2 * lane + 1], 0.f);
    hbf[(size_t)n * 64 + lane] = pack_bf2(r0, r1);
}

// ---------------- mean-pool per graph (seg sorted -> contiguous ranges) ----------------
__device__ __forceinline__ int lower_bound_seg(const int* __restrict__ seg, int val) {
    int lo = 0, hi = NN;
    while (lo < hi) {
        int m = (lo + hi) >> 1;
        if (seg[m] < val) lo = m + 1; else hi = m;
    }
    return lo;
}

__global__ __launch_bounds__(1024) void pool_k(const uint* __restrict__ hbf,
                                               const int* __restrict__ seg1, const int* __restrict__ seg2,
                                               float* __restrict__ out) {
    __shared__ int sb[2];
    __shared__ float2 buf[16 * 64];
    int g = blockIdx.x;            // 0..255
    int br = g >> 7;
    int gg = g & 127;
    const int* seg = br ? seg2 : seg1;
    int t = threadIdx.x;
    if (t < 2) sb[t] = lower_bound_seg(seg, gg + t);
    __syncthreads();
    int beg = sb[0], end = sb[1];
    int u = t & 63, part = t >> 6;   // 16 parts
    size_t base = (size_t)br * NN;
    float ax = 0.f, ay = 0.f;
    for (int n = beg + part; n < end; n += 16) {
        uint v = hbf[(base + n) * 64 + u];
        ax += bf_lo(v);
        ay += bf_hi(v);
    }
    buf[part * 64 + u] = make_float2(ax, ay);
    __syncthreads();
    if (part == 0) {
        float2 s = buf[u];
#pragma unroll
        for (int i = 1; i < 16; i++) { s.x += buf[i * 64 + u].x; s.y += buf[i * 64 + u].y; }
        float inv = 1.f / fmaxf((float)(end - beg), 1.f);
        out[g * HID + 2 * u] = s.x * inv;
        out[g * HID + 2 * u + 1] = s.y * inv;
    }
}

// ---------------- |hg1-hg2| @ Wc + bc ----------------
__global__ __launch_bounds__(128) void logits_k(const float* __restrict__ out_hg,
                                                const float* __restrict__ Wc,
                                                const float* __restrict__ bc,
                                                float* __restrict__ logits) {
    __shared__ float d[HID];
    int g = blockIdx.x;
    int t = threadIdx.x;
    d[t] = fabsf(out_hg[g * HID + t] - out_hg[NG * HID + g * HID + t]);
    __syncthreads();
    if (t < NC) {
        float a = bc[t];
        for (int k = 0; k < HID; k++) a += d[k] * Wc[k * NC + t];
        logits[g * NC + t] = a;
    }
}

extern "C" void kernel_launch(void* const* d_in, const int* in_sizes, int n_in,
                              void* d_out, int out_size, void* d_ws, size_t ws_size,
                              hipStream_t stream) {
    const int* src1 = (const int*)d_in[0];
    const int* dst1 = (const int*)d_in[1];
    const int* seg1 = (const int*)d_in[2];
    const int* src2 = (const int*)d_in[3];
    const int* dst2 = (const int*)d_in[4];
    const int* seg2 = (const int*)d_in[5];
    const float* W1 = (const float*)d_in[6];
    const float* b1 = (const float*)d_in[7];
    const float* Wl[3] = { (const float*)d_in[8], (const float*)d_in[10], (const float*)d_in[12] };
    const float* bl[3] = { (const float*)d_in[9], (const float*)d_in[11], (const float*)d_in[13] };
    const float* Wc = (const float*)d_in[14];
    const float* bc = (const float*)d_in[15];
    float* out = (float*)d_out;

    // ---- workspace layout ----
    uint* hbf = (uint*)d_ws;                        // NT*64 (bf16x2 packed h)
    uint* pbf = hbf + (size_t)NT * 64;              // NT*64 (bf16x2 packed p)
    int* col       = (int*)(pbf + (size_t)NT * 64); // ET
    int* row_start = col + ET;                      // NT+1
    int* cursor    = row_start + NT + 2;            // NT
    int* cnt_out   = cursor + NT;                   // NT
    int* cnt_in    = cnt_out + NT;                  // NT (contiguous with cnt_out)
    float* cs   = (float*)(cnt_in + NT);            // NT
    float* cd   = cs + NT;                          // NT
    float* s0   = cd + NT;                          // NT
    float* aggs = s0 + NT;                          // NT
    int* bsum   = (int*)(aggs + NT);                // SCAN_NB
    int* boff   = bsum + SCAN_NB;                   // SCAN_NB

    hipMemsetAsync(cnt_out, 0, 2 * NT * sizeof(int), stream);

    hist_k<<<ET / 256, 256, 0, stream>>>(src1, dst1, src2, dst2, cnt_out, cnt_in);
    scan_reduce_k<<<SCAN_NB, 1024, 0, stream>>>(cnt_in, bsum);
    scan_partials_k<<<1, 256, 0, stream>>>(bsum, boff, row_start);
    scan_final_k<<<SCAN_NB, 1024, 0, stream>>>(cnt_in, boff, row_start);
    node_prep_k<<<(NT + 255) / 256, 256, 0, stream>>>(cnt_out, cnt_in, row_start, cs, cd, s0, cursor);
    fill_k<<<ET / 256, 256, 0, stream>>>(src1, dst1, src2, dst2, cursor, col);

    // layer 1 (rank-1)
    l1_agg_k<<<(NT + 255) / 256, 256, 0, stream>>>(row_start, col, s0, cd, aggs);
    l1_expand_k<<<(NT * 64) / 256, 256, 0, stream>>>(aggs, W1, b1, hbf);

    // layers 2..4 (MFMA GEMM + gather-aggregate)
    for (int l = 0; l < 3; l++) {
        gemm_k<<<NT / 64, 256, 0, stream>>>(hbf, Wl[l], cs, pbf);
        agg_relu_k<<<NT / 4, 256, 0, stream>>>(pbf, row_start, col, cd, bl[l], hbf);
    }

    // mean pool (both branches), writes hg1|hg2 directly
    pool_k<<<2 * NG, 1024, 0, stream>>>(hbf, seg1, seg2, out);

    logits_k<<<NG, 128, 0, stream>>>(out, Wc, bc, out + 2 * NG * HID);
}

// Round 5
// 973.954 us; speedup vs baseline: 3.3887x; 1.2087x over previous
//
#include <hip/hip_runtime.h>

#define NN 100000
#define NE 1600000
#define NT (2 * NN)
#define ET (2 * NE)
#define NG 128
#define HID 128
#define NC 10
#define SCAN_NB ((NT + 1023) / 1024)   // 196
#define BUK_SHIFT 9
#define NBUK ((NT + 511) >> 9)         // 391
#define CHUNK 8192
#define BINB ((ET + CHUNK - 1) / CHUNK) // 391

typedef unsigned int uint;
typedef __attribute__((ext_vector_type(8))) short bf16x8;
typedef __attribute__((ext_vector_type(4))) float f32x4;

union U8 { uint4 u; bf16x8 v; };

__device__ __forceinline__ float bf_lo(uint v) { return __uint_as_float(v << 16); }
__device__ __forceinline__ float bf_hi(uint v) { return __uint_as_float(v & 0xffff0000u); }
__device__ __forceinline__ uint bf_round16(float x) {   // 16-bit bf16 value (RNE)
    uint ux = __float_as_uint(x);
    return (ux + 0x7fffu + ((ux >> 16) & 1u)) >> 16;
}
__device__ __forceinline__ uint pack_bf2(float x, float y) {
    return bf_round16(x) | (bf_round16(y) << 16);
}

// ---------------- degree histograms, both branches ----------------
__global__ __launch_bounds__(256) void hist_k(const int* __restrict__ src1, const int* __restrict__ dst1,
                                              const int* __restrict__ src2, const int* __restrict__ dst2,
                                              int* __restrict__ cnt_out, int* __restrict__ cnt_in) {
    int e = blockIdx.x * 256 + threadIdx.x;          // 0 .. ET
    int br = (e >= NE);                               // block-uniform (NE % 256 == 0)
    int ee = br ? e - NE : e;
    int s = br ? src2[ee] + NN : src1[ee];
    int d = br ? dst2[ee] + NN : dst1[ee];
    atomicAdd(&cnt_out[s], 1);
    atomicAdd(&cnt_in[d], 1);
}

// ---------------- 3-kernel exclusive scan of cnt_in -> row_start ----------------
__global__ __launch_bounds__(1024) void scan_reduce_k(const int* __restrict__ cnt, int* __restrict__ bsum) {
    __shared__ int ws[16];
    int t = threadIdx.x;
    int idx = blockIdx.x * 1024 + t;
    int v = (idx < NT) ? cnt[idx] : 0;
#pragma unroll
    for (int d = 1; d < 64; d <<= 1) v += __shfl_xor(v, d, 64);
    if ((t & 63) == 0) ws[t >> 6] = v;
    __syncthreads();
    if (t == 0) {
        int s = 0;
#pragma unroll
        for (int i = 0; i < 16; i++) s += ws[i];
        bsum[blockIdx.x] = s;
    }
}

__global__ __launch_bounds__(256) void scan_partials_k(const int* __restrict__ bsum,
                                                       int* __restrict__ boff,
                                                       int* __restrict__ row_start) {
    __shared__ int ws[4];
    int t = threadIdx.x;
    int lane = t & 63, wid = t >> 6;
    int v = (t < SCAN_NB) ? bsum[t] : 0;
    int x = v;
#pragma unroll
    for (int d = 1; d < 64; d <<= 1) { int y = __shfl_up(x, d, 64); if (lane >= d) x += y; }
    if (lane == 63) ws[wid] = x;
    __syncthreads();
    int off = 0;
    for (int i = 0; i < wid; i++) off += ws[i];
    if (t < SCAN_NB) boff[t] = off + x - v;
    if (t == 0) row_start[NT] = ET;
}

__global__ __launch_bounds__(1024) void scan_final_k(const int* __restrict__ cnt,
                                                     const int* __restrict__ boff,
                                                     int* __restrict__ row_start) {
    __shared__ int ws[16];
    int t = threadIdx.x;
    int lane = t & 63, wid = t >> 6;
    int idx = blockIdx.x * 1024 + t;
    int v = (idx < NT) ? cnt[idx] : 0;
    int x = v;
#pragma unroll
    for (int d = 1; d < 64; d <<= 1) { int y = __shfl_up(x, d, 64); if (lane >= d) x += y; }
    if (lane == 63) ws[wid] = x;
    __syncthreads();
    if (t == 0) {
        int s = 0;
#pragma unroll
        for (int i = 0; i < 16; i++) { int tmp = ws[i]; ws[i] = s; s += tmp; }
    }
    __syncthreads();
    if (idx < NT) row_start[idx] = boff[blockIdx.x] + ws[wid] + (x - v);
}

// ---------------- per-node: cs, cd, h0*cs; bucket cursor init ----------------
__global__ __launch_bounds__(256) void node_prep_k(const int* __restrict__ cnt_out,
                                                   const int* __restrict__ cnt_in,
                                                   const int* __restrict__ row_start,
                                                   float* __restrict__ cs, float* __restrict__ cd,
                                                   float* __restrict__ s0, int* __restrict__ bcursor) {
    int n = blockIdx.x * 256 + threadIdx.x;
    if (n < NT) {
        float od = (float)cnt_out[n];
        float idg = (float)cnt_in[n];
        float c_s = rsqrtf(fmaxf(od, 1.f));
        cs[n] = c_s;
        cd[n] = rsqrtf(fmaxf(idg, 1.f));
        s0[n] = idg * c_s;
    }
    if (n < NBUK) bcursor[n] = row_start[n << BUK_SHIFT];
}

// ---------------- binned CSC build: pass 1 — bin (dst,src) pairs by dst>>9 ----------------
__global__ __launch_bounds__(256) void bin_k(const int* __restrict__ src1, const int* __restrict__ dst1,
                                             const int* __restrict__ src2, const int* __restrict__ dst2,
                                             int* __restrict__ bcursor, uint2* __restrict__ pairs) {
    __shared__ int hist[NBUK];
    __shared__ int lofs[NBUK];
    __shared__ int gbase[NBUK];
    __shared__ int cnt2[NBUK];
    __shared__ uint2 stag[CHUNK];
    int t = threadIdx.x;
    int e0 = blockIdx.x * CHUNK;
    int ecnt = min(CHUNK, ET - e0);
    for (int i = t; i < NBUK; i += 256) { hist[i] = 0; cnt2[i] = 0; }
    __syncthreads();
    // phase 1: bucket histogram
    for (int j = t; j < ecnt; j += 256) {
        int e = e0 + j;
        int d = (e >= NE) ? dst2[e - NE] + NN : dst1[e];
        atomicAdd(&hist[d >> BUK_SHIFT], 1);
    }
    __syncthreads();
    // phase 2: single-wave scan hist -> lofs
    if (t < 64) {
        int carry = 0;
        for (int base = 0; base < NBUK; base += 64) {
            int i = base + t;
            int v = (i < NBUK) ? hist[i] : 0;
            int x = v;
#pragma unroll
            for (int d = 1; d < 64; d <<= 1) { int y = __shfl_up(x, d, 64); if (t >= d) x += y; }
            if (i < NBUK) lofs[i] = carry + x - v;
            carry += __shfl(x, 63, 64);
        }
    }
    __syncthreads();
    // phase 2b: reserve global space per bucket
    for (int i = t; i < NBUK; i += 256) {
        int c = hist[i];
        gbase[i] = c ? atomicAdd(&bcursor[i], c) : 0;
    }
    __syncthreads();
    // phase 3: local bucket-sort into LDS staging
    for (int j = t; j < ecnt; j += 256) {
        int e = e0 + j;
        int s, d;
        if (e >= NE) { s = src2[e - NE] + NN; d = dst2[e - NE] + NN; }
        else         { s = src1[e];           d = dst1[e]; }
        int b = d >> BUK_SHIFT;
        int r = lofs[b] + atomicAdd(&cnt2[b], 1);
        stag[r] = make_uint2((uint)d, (uint)s);
    }
    __syncthreads();
    // phase 4: coalesced-run flush
    for (int i = t; i < ecnt; i += 256) {
        uint2 pr = stag[i];
        int b = (int)pr.x >> BUK_SHIFT;
        pairs[gbase[b] + (i - lofs[b])] = pr;
    }
}

// ---------------- binned CSC build: pass 2 — per-bucket scatter to col ----------------
__global__ __launch_bounds__(256) void scatter_k(const uint2* __restrict__ pairs,
                                                 const int* __restrict__ row_start,
                                                 int* __restrict__ col) {
    __shared__ int cur[512];
    int b = blockIdx.x;
    int t = threadIdx.x;
    int n0 = b << BUK_SHIFT;
    int ncnt = min(512, NT - n0);
    for (int j = t; j < ncnt; j += 256) cur[j] = row_start[n0 + j];
    __syncthreads();
    int gs = row_start[n0];
    int ge = row_start[min(n0 + 512, NT)];
    for (int i = gs + t; i < ge; i += 256) {
        uint2 pr = pairs[i];
        int pos = atomicAdd(&cur[(int)pr.x - n0], 1);
        col[pos] = (int)pr.y;
    }
}

// ---------------- layer-1 scalar aggregation ----------------
__global__ __launch_bounds__(256) void l1_agg_k(const int* __restrict__ row_start, const int* __restrict__ col,
                                                const float* __restrict__ s0, const float* __restrict__ cd,
                                                float* __restrict__ aggs) {
    int n = blockIdx.x * 256 + threadIdx.x;
    if (n < NT) {
        int b = row_start[n], e = row_start[n + 1];
        float a = 0.f;
        for (int i = b; i < e; i++) a += s0[col[i]];
        aggs[n] = a * cd[n];
    }
}

// ---------------- layer-1 rank-1 expand -> packed bf16 h ----------------
__global__ __launch_bounds__(256) void l1_expand_k(const float* __restrict__ aggs,
                                                   const float* __restrict__ W1, const float* __restrict__ b1,
                                                   uint* __restrict__ hbf) {
    int i = blockIdx.x * 256 + threadIdx.x;   // NT*64 exact
    int u = i & 63;
    int n = i >> 6;
    float a = aggs[n];
    float v0 = fmaxf(a * W1[2 * u] + b1[2 * u], 0.f);
    float v1 = fmaxf(a * W1[2 * u + 1] + b1[2 * u + 1], 0.f);
    hbf[i] = pack_bf2(v0, v1);
}

// ---------------- MFMA GEMM: pbf[n] = bf16( cs[n] * (h[n] @ W) ) ----------------
// W split into bf16 hi+lo planes staged in LDS in B-fragment layout.
__global__ __launch_bounds__(256) void gemm_k(const uint* __restrict__ hbf, const float* __restrict__ W,
                                              const float* __restrict__ cs, uint* __restrict__ pbf) {
    __shared__ uint4 Bh[32 * 64];   // 32 KB
    __shared__ uint4 Bl[32 * 64];   // 32 KB
    int t = threadIdx.x;
    int lane = t & 63;

    for (int s = t >> 6; s < 32; s += 4) {
        int ks = s >> 3, n0 = s & 7;
        int k0 = ks * 32 + (lane >> 4) * 8;
        int c = n0 * 16 + (lane & 15);
        uint4 hv, lv;
        uint* hp = (uint*)&hv;
        uint* lp = (uint*)&lv;
#pragma unroll
        for (int g = 0; g < 4; g++) {
            float w0 = W[(k0 + 2 * g) * HID + c];
            float w1 = W[(k0 + 2 * g + 1) * HID + c];
            uint h0 = bf_round16(w0), h1 = bf_round16(w1);
            float r0 = w0 - __uint_as_float(h0 << 16);
            float r1 = w1 - __uint_as_float(h1 << 16);
            hp[g] = h0 | (h1 << 16);
            lp[g] = pack_bf2(r0, r1);
        }
        Bh[s * 64 + lane] = hv;
        Bl[s * 64 + lane] = lv;
    }
    __syncthreads();

    int wv = t >> 6;
    int m0w = blockIdx.x * 64 + wv * 16;           // NT % 64 == 0
    int row = m0w + (lane & 15);
    int quad = lane >> 4;

    U8 a[4];
#pragma unroll
    for (int ks = 0; ks < 4; ks++)
        a[ks].u = *(const uint4*)&hbf[(size_t)row * 64 + ks * 16 + quad * 4];

    f32x4 acc[8];
#pragma unroll
    for (int i = 0; i < 8; i++) acc[i] = (f32x4)(0.f);

#pragma unroll
    for (int ks = 0; ks < 4; ks++) {
#pragma unroll
        for (int n0 = 0; n0 < 8; n0++) {
            U8 b;
            b.u = Bh[(ks * 8 + n0) * 64 + lane];
            acc[n0] = __builtin_amdgcn_mfma_f32_16x16x32_bf16(a[ks].v, b.v, acc[n0], 0, 0, 0);
        }
#pragma unroll
        for (int n0 = 0; n0 < 8; n0++) {
            U8 b;
            b.u = Bl[(ks * 8 + n0) * 64 + lane];
            acc[n0] = __builtin_amdgcn_mfma_f32_16x16x32_bf16(a[ks].v, b.v, acc[n0], 0, 0, 0);
        }
    }

    float4 cs4 = *(const float4*)&cs[m0w + quad * 4];
    const float csr[4] = { cs4.x, cs4.y, cs4.z, cs4.w };
#pragma unroll
    for (int n0 = 0; n0 < 8; n0++) {
#pragma unroll
        for (int r = 0; r < 4; r++) {
            float v = acc[n0][r] * csr[r];
            float partner = __shfl_xor(v, 1, 64);
            if (!(lane & 1)) {
                int rg = m0w + quad * 4 + r;
                pbf[(size_t)rg * 64 + n0 * 8 + ((lane & 15) >> 1)] = pack_bf2(v, partner);
            }
        }
    }
}

// ---------------- aggregate bf16 p over incoming edges, relu, write bf16 h ----------------
__global__ __launch_bounds__(256) void agg_relu_k(const uint* __restrict__ pbf,
                                                  const int* __restrict__ row_start,
                                                  const int* __restrict__ col,
                                                  const float* __restrict__ cd,
                                                  const float* __restrict__ b,
                                                  uint* __restrict__ hbf) {
    int t = threadIdx.x;
    int lane = t & 63;
    int n = blockIdx.x * 4 + (t >> 6);
    int beg = __builtin_amdgcn_readfirstlane(row_start[n]);
    int end = __builtin_amdgcn_readfirstlane(row_start[n + 1]);
    float ax = 0.f, ay = 0.f;
    int i = beg;
    for (; i + 4 <= end; i += 4) {
        int c0 = col[i], c1 = col[i + 1], c2 = col[i + 2], c3 = col[i + 3];
        uint v0 = pbf[(size_t)c0 * 64 + lane];
        uint v1 = pbf[(size_t)c1 * 64 + lane];
        uint v2 = pbf[(size_t)c2 * 64 + lane];
        uint v3 = pbf[(size_t)c3 * 64 + lane];
        ax += bf_lo(v0) + bf_lo(v1) + bf_lo(v2) + bf_lo(v3);
        ay += bf_hi(v0) + bf_hi(v1) + bf_hi(v2) + bf_hi(v3);
    }
    for (; i < end; i++) {
        uint v = pbf[(size_t)col[i] * 64 + lane];
        ax += bf_lo(v);
        ay += bf_hi(v);
    }
    float s = cd[n];
    float r0 = fmaxf(ax * s + b[2 * lane], 0.f);
    float r1 = fmaxf(ay * s + b[2 * lane + 1], 0.f);
    hbf[(size_t)n * 64 + lane] = pack_bf2(r0, r1);
}

// ---------------- mean-pool per graph ----------------
__device__ __forceinline__ int lower_bound_seg(const int* __restrict__ seg, int val) {
    int lo = 0, hi = NN;
    while (lo < hi) {
        int m = (lo + hi) >> 1;
        if (seg[m] < val) lo = m + 1; else hi = m;
    }
    return lo;
}

__global__ __launch_bounds__(1024) void pool_k(const uint* __restrict__ hbf,
                                               const int* __restrict__ seg1, const int* __restrict__ seg2,
                                               float* __restrict__ out) {
    __shared__ int sb[2];
    __shared__ float2 buf[16 * 64];
    int g = blockIdx.x;            // 0..255
    int br = g >> 7;
    int gg = g & 127;
    const int* seg = br ? seg2 : seg1;
    int t = threadIdx.x;
    if (t < 2) sb[t] = lower_bound_seg(seg, gg + t);
    __syncthreads();
    int beg = sb[0], end = sb[1];
    int u = t & 63, part = t >> 6;   // 16 parts
    size_t base = (size_t)br * NN;
    float ax = 0.f, ay = 0.f;
    for (int n = beg + part; n < end; n += 16) {
        uint v = hbf[(base + n) * 64 + u];
        ax += bf_lo(v);
        ay += bf_hi(v);
    }
    buf[part * 64 + u] = make_float2(ax, ay);
    __syncthreads();
    if (part == 0) {
        float2 s = buf[u];
#pragma unroll
        for (int i = 1; i < 16; i++) { s.x += buf[i * 64 + u].x; s.y += buf[i * 64 + u].y; }
        float inv = 1.f / fmaxf((float)(end - beg), 1.f);
        out[g * HID + 2 * u] = s.x * inv;
        out[g * HID + 2 * u + 1] = s.y * inv;
    }
}

// ---------------- |hg1-hg2| @ Wc + bc ----------------
__global__ __launch_bounds__(128) void logits_k(const float* __restrict__ out_hg,
                                                const float* __restrict__ Wc,
                                                const float* __restrict__ bc,
                                                float* __restrict__ logits) {
    __shared__ float d[HID];
    int g = blockIdx.x;
    int t = threadIdx.x;
    d[t] = fabsf(out_hg[g * HID + t] - out_hg[NG * HID + g * HID + t]);
    __syncthreads();
    if (t < NC) {
        float a = bc[t];
        for (int k = 0; k < HID; k++) a += d[k] * Wc[k * NC + t];
        logits[g * NC + t] = a;
    }
}

extern "C" void kernel_launch(void* const* d_in, const int* in_sizes, int n_in,
                              void* d_out, int out_size, void* d_ws, size_t ws_size,
                              hipStream_t stream) {
    const int* src1 = (const int*)d_in[0];
    const int* dst1 = (const int*)d_in[1];
    const int* seg1 = (const int*)d_in[2];
    const int* src2 = (const int*)d_in[3];
    const int* dst2 = (const int*)d_in[4];
    const int* seg2 = (const int*)d_in[5];
    const float* W1 = (const float*)d_in[6];
    const float* b1 = (const float*)d_in[7];
    const float* Wl[3] = { (const float*)d_in[8], (const float*)d_in[10], (const float*)d_in[12] };
    const float* bl[3] = { (const float*)d_in[9], (const float*)d_in[11], (const float*)d_in[13] };
    const float* Wc = (const float*)d_in[14];
    const float* bc = (const float*)d_in[15];
    float* out = (float*)d_out;

    // ---- workspace layout ----
    uint* hbf = (uint*)d_ws;                        // NT*64 (bf16x2 packed h)
    uint* pbf = hbf + (size_t)NT * 64;              // NT*64 (bf16x2 packed p); pairs alias
    uint2* pairs = (uint2*)pbf;                     // ET uint2 (25.6 MB <= 51.2 MB)
    int* col       = (int*)(pbf + (size_t)NT * 64); // ET
    int* row_start = col + ET;                      // NT+1
    int* bcursor   = row_start + NT + 2;            // NBUK
    int* cnt_out   = bcursor + NBUK + 2;            // NT
    int* cnt_in    = cnt_out + NT;                  // NT (contiguous with cnt_out)
    float* cs   = (float*)(cnt_in + NT);            // NT
    float* cd   = cs + NT;                          // NT
    float* s0   = cd + NT;                          // NT
    float* aggs = s0 + NT;                          // NT
    int* bsum   = (int*)(aggs + NT);                // SCAN_NB
    int* boff   = bsum + SCAN_NB;                   // SCAN_NB

    hipMemsetAsync(cnt_out, 0, 2 * NT * sizeof(int), stream);

    hist_k<<<ET / 256, 256, 0, stream>>>(src1, dst1, src2, dst2, cnt_out, cnt_in);
    scan_reduce_k<<<SCAN_NB, 1024, 0, stream>>>(cnt_in, bsum);
    scan_partials_k<<<1, 256, 0, stream>>>(bsum, boff, row_start);
    scan_final_k<<<SCAN_NB, 1024, 0, stream>>>(cnt_in, boff, row_start);
    node_prep_k<<<(NT + 255) / 256, 256, 0, stream>>>(cnt_out, cnt_in, row_start, cs, cd, s0, bcursor);
    bin_k<<<BINB, 256, 0, stream>>>(src1, dst1, src2, dst2, bcursor, pairs);
    scatter_k<<<NBUK, 256, 0, stream>>>(pairs, row_start, col);

    // layer 1 (rank-1)
    l1_agg_k<<<(NT + 255) / 256, 256, 0, stream>>>(row_start, col, s0, cd, aggs);
    l1_expand_k<<<(NT * 64) / 256, 256, 0, stream>>>(aggs, W1, b1, hbf);

    // layers 2..4 (MFMA GEMM + gather-aggregate)
    for (int l = 0; l < 3; l++) {
        gemm_k<<<NT / 64, 256, 0, stream>>>(hbf, Wl[l], cs, pbf);
        agg_relu_k<<<NT / 4, 256, 0, stream>>>(pbf, row_start, col, cd, bl[l], hbf);
    }

    // mean pool (both branches), writes hg1|hg2 directly
    pool_k<<<2 * NG, 1024, 0, stream>>>(hbf, seg1, seg2, out);

    logits_k<<<NG, 128, 0, stream>>>(out, Wc, bc, out + 2 * NG * HID);
}

// Round 6
// 760.061 us; speedup vs baseline: 4.3423x; 1.2814x over previous
//
#include <hip/hip_runtime.h>

#define NN 100000
#define NE 1600000
#define NT (2 * NN)
#define ET (2 * NE)
#define NG 128
#define HID 128
#define NC 10
#define BUK_SHIFT 9
#define NBUK ((NT + 511) >> 9)          // 391
#define CHUNK 8192
#define BINB ((ET + CHUNK - 1) / CHUNK) // 391
#define CAP 10240                        // per-bucket region capacity (mean ~8184, 22 sigma)

typedef unsigned int uint;
typedef unsigned short ushort;
typedef __attribute__((ext_vector_type(8))) short bf16x8;
typedef __attribute__((ext_vector_type(4))) float f32x4;

union U8 { uint4 u; bf16x8 v; };

__device__ __forceinline__ float bf_lo(uint v) { return __uint_as_float(v << 16); }
__device__ __forceinline__ float bf_hi(uint v) { return __uint_as_float(v & 0xffff0000u); }
__device__ __forceinline__ uint bf_round16(float x) {   // 16-bit bf16 value (RNE)
    uint ux = __float_as_uint(x);
    return (ux + 0x7fffu + ((ux >> 16) & 1u)) >> 16;
}
__device__ __forceinline__ uint pack_bf2(float x, float y) {
    return bf_round16(x) | (bf_round16(y) << 16);
}

// ---------------- bin (dst,src) pairs by dst bucket (fixed-capacity regions) ----------------
__global__ __launch_bounds__(256) void bin_dst_k(const int* __restrict__ src1, const int* __restrict__ dst1,
                                                 const int* __restrict__ src2, const int* __restrict__ dst2,
                                                 int* __restrict__ bcount_d, uint* __restrict__ pairs) {
    __shared__ int hist[NBUK];
    __shared__ int lofs[NBUK];
    __shared__ int gbase[NBUK];
    __shared__ int cnt2[NBUK];
    __shared__ uint2 stag[CHUNK];
    int t = threadIdx.x;
    int e0 = blockIdx.x * CHUNK;
    int ecnt = min(CHUNK, ET - e0);
    for (int i = t; i < NBUK; i += 256) { hist[i] = 0; cnt2[i] = 0; }
    __syncthreads();
    for (int j = t; j < ecnt; j += 256) {
        int e = e0 + j;
        int d = (e >= NE) ? dst2[e - NE] + NN : dst1[e];
        atomicAdd(&hist[d >> BUK_SHIFT], 1);
    }
    __syncthreads();
    if (t < 64) {                       // single-wave scan hist -> lofs
        int carry = 0;
        for (int base = 0; base < NBUK; base += 64) {
            int i = base + t;
            int v = (i < NBUK) ? hist[i] : 0;
            int x = v;
#pragma unroll
            for (int d = 1; d < 64; d <<= 1) { int y = __shfl_up(x, d, 64); if (t >= d) x += y; }
            if (i < NBUK) lofs[i] = carry + x - v;
            carry += __shfl(x, 63, 64);
        }
    }
    __syncthreads();
    for (int i = t; i < NBUK; i += 256) {
        int c = hist[i];
        gbase[i] = c ? (CAP * i + atomicAdd(&bcount_d[i], c)) : 0;
    }
    __syncthreads();
    for (int j = t; j < ecnt; j += 256) {
        int e = e0 + j;
        int s, d;
        if (e >= NE) { s = src2[e - NE] + NN; d = dst2[e - NE] + NN; }
        else         { s = src1[e];           d = dst1[e]; }
        int b = d >> BUK_SHIFT;
        int r = lofs[b] + atomicAdd(&cnt2[b], 1);
        stag[r] = make_uint2((uint)d, (uint)s);
    }
    __syncthreads();
    for (int i = t; i < ecnt; i += 256) {
        uint2 pr = stag[i];
        int b = (int)pr.x >> BUK_SHIFT;
        pairs[gbase[b] + (i - lofs[b])] = ((pr.x & 511u) << 18) | pr.y;
    }
}

// ---------------- bin src ids by src bucket (for out-degree counting) ----------------
__global__ __launch_bounds__(256) void bin_src_k(const int* __restrict__ src1, const int* __restrict__ src2,
                                                 int* __restrict__ bcount_s, ushort* __restrict__ vals) {
    __shared__ int hist[NBUK];
    __shared__ int lofs[NBUK];
    __shared__ int gbase[NBUK];
    __shared__ int cnt2[NBUK];
    __shared__ uint stag[CHUNK];
    int t = threadIdx.x;
    int e0 = blockIdx.x * CHUNK;
    int ecnt = min(CHUNK, ET - e0);
    for (int i = t; i < NBUK; i += 256) { hist[i] = 0; cnt2[i] = 0; }
    __syncthreads();
    for (int j = t; j < ecnt; j += 256) {
        int e = e0 + j;
        int s = (e >= NE) ? src2[e - NE] + NN : src1[e];
        atomicAdd(&hist[s >> BUK_SHIFT], 1);
    }
    __syncthreads();
    if (t < 64) {
        int carry = 0;
        for (int base = 0; base < NBUK; base += 64) {
            int i = base + t;
            int v = (i < NBUK) ? hist[i] : 0;
            int x = v;
#pragma unroll
            for (int d = 1; d < 64; d <<= 1) { int y = __shfl_up(x, d, 64); if (t >= d) x += y; }
            if (i < NBUK) lofs[i] = carry + x - v;
            carry += __shfl(x, 63, 64);
        }
    }
    __syncthreads();
    for (int i = t; i < NBUK; i += 256) {
        int c = hist[i];
        gbase[i] = c ? (CAP * i + atomicAdd(&bcount_s[i], c)) : 0;
    }
    __syncthreads();
    for (int j = t; j < ecnt; j += 256) {
        int e = e0 + j;
        int s = (e >= NE) ? src2[e - NE] + NN : src1[e];
        int b = s >> BUK_SHIFT;
        int r = lofs[b] + atomicAdd(&cnt2[b], 1);
        stag[r] = (uint)s;
    }
    __syncthreads();
    for (int i = t; i < ecnt; i += 256) {
        uint v = stag[i];
        int b = (int)(v >> BUK_SHIFT);
        vals[gbase[b] + (i - lofs[b])] = (ushort)(v & 511u);
    }
}

// ---------------- scan bucket counts -> bucket bases ----------------
__global__ __launch_bounds__(64) void bucket_scan_k(const int* __restrict__ bcount_d,
                                                    int* __restrict__ bbase,
                                                    int* __restrict__ row_start) {
    int t = threadIdx.x;
    int carry = 0;
    for (int base = 0; base < NBUK; base += 64) {
        int i = base + t;
        int v = (i < NBUK) ? bcount_d[i] : 0;
        int x = v;
#pragma unroll
        for (int d = 1; d < 64; d <<= 1) { int y = __shfl_up(x, d, 64); if (t >= d) x += y; }
        if (i < NBUK) bbase[i] = carry + x - v;
        carry += __shfl(x, 63, 64);
    }
    if (t == 0) row_start[NT] = ET;
}

// ---------------- per-bucket: degrees -> cs/cd/s0, local scan -> row_start, sorted col ----------------
__global__ __launch_bounds__(256) void build_k(const uint* __restrict__ pairs, const ushort* __restrict__ vals,
                                               const int* __restrict__ bcount_d, const int* __restrict__ bcount_s,
                                               const int* __restrict__ bbase_a,
                                               int* __restrict__ row_start, float* __restrict__ cs,
                                               float* __restrict__ cd, float* __restrict__ s0,
                                               int* __restrict__ col) {
    __shared__ int hs[512], hd[512];
    __shared__ int cur[512];
    __shared__ int wsum[4];
    __shared__ uint cstage[CAP];
    int b = blockIdx.x, t = threadIdx.x;
    int n0 = b << BUK_SHIFT;
    int ncnt = min(512, NT - n0);
    int ecnt = bcount_d[b];
    int scnt = bcount_s[b];
    int base_off = bbase_a[b];
    for (int j = t; j < 512; j += 256) { hs[j] = 0; hd[j] = 0; }
    __syncthreads();
    const ushort* vb = vals + (size_t)b * CAP;
    for (int i = t; i < scnt; i += 256) atomicAdd(&hs[vb[i]], 1);
    const uint* pb = pairs + (size_t)b * CAP;
    for (int i = t; i < ecnt; i += 256) atomicAdd(&hd[pb[i] >> 18], 1);
    __syncthreads();
    // per-node outputs
    for (int j = t; j < ncnt; j += 256) {
        float csl = rsqrtf(fmaxf((float)hs[j], 1.f));
        cs[n0 + j] = csl;
        int di = hd[j];
        cd[n0 + j] = rsqrtf(fmaxf((float)di, 1.f));
        s0[n0 + j] = (float)di * csl;
    }
    // exclusive scan of hd[0..511]: 2 elements/thread
    int a0 = hd[2 * t], a1 = hd[2 * t + 1];
    int ps = a0 + a1;
    int lane = t & 63, w = t >> 6;
    int x = ps;
#pragma unroll
    for (int d = 1; d < 64; d <<= 1) { int y = __shfl_up(x, d, 64); if (lane >= d) x += y; }
    if (lane == 63) wsum[w] = x;
    __syncthreads();
    int off = 0;
    for (int i = 0; i < w; i++) off += wsum[i];
    int ep = off + x - ps;
    cur[2 * t] = ep;
    cur[2 * t + 1] = ep + a0;
    if (2 * t < ncnt) row_start[n0 + 2 * t] = base_off + ep;
    if (2 * t + 1 < ncnt) row_start[n0 + 2 * t + 1] = base_off + ep + a0;
    __syncthreads();
    // scatter into LDS stage via per-node cursors
    for (int i = t; i < ecnt; i += 256) {
        uint v = pb[i];
        int pos = atomicAdd(&cur[v >> 18], 1);
        cstage[pos] = v & 0x3FFFFu;
    }
    __syncthreads();
    // coalesced flush
    for (int i = t; i < ecnt; i += 256) col[base_off + i] = (int)cstage[i];
}

// ---------------- layer-1 scalar aggregation ----------------
__global__ __launch_bounds__(256) void l1_agg_k(const int* __restrict__ row_start, const int* __restrict__ col,
                                                const float* __restrict__ s0, const float* __restrict__ cd,
                                                float* __restrict__ aggs) {
    int n = blockIdx.x * 256 + threadIdx.x;
    if (n < NT) {
        int b = row_start[n], e = row_start[n + 1];
        float a = 0.f;
        for (int i = b; i < e; i++) a += s0[col[i]];
        aggs[n] = a * cd[n];
    }
}

// ---------------- layer-1 rank-1 expand -> packed bf16 h ----------------
__global__ __launch_bounds__(256) void l1_expand_k(const float* __restrict__ aggs,
                                                   const float* __restrict__ W1, const float* __restrict__ b1,
                                                   uint* __restrict__ hbf) {
    int i = blockIdx.x * 256 + threadIdx.x;   // NT*64 exact
    int u = i & 63;
    int n = i >> 6;
    float a = aggs[n];
    float v0 = fmaxf(a * W1[2 * u] + b1[2 * u], 0.f);
    float v1 = fmaxf(a * W1[2 * u + 1] + b1[2 * u + 1], 0.f);
    hbf[i] = pack_bf2(v0, v1);
}

// ---------------- MFMA GEMM: pbf[n] = bf16( cs[n] * (h[n] @ W) ) ----------------
// W split into bf16 hi+lo planes staged in LDS in B-fragment layout.
__global__ __launch_bounds__(256) void gemm_k(const uint* __restrict__ hbf, const float* __restrict__ W,
                                              const float* __restrict__ cs, uint* __restrict__ pbf) {
    __shared__ uint4 Bh[32 * 64];   // 32 KB
    __shared__ uint4 Bl[32 * 64];   // 32 KB
    int t = threadIdx.x;
    int lane = t & 63;

    for (int s = t >> 6; s < 32; s += 4) {
        int ks = s >> 3, n0 = s & 7;
        int k0 = ks * 32 + (lane >> 4) * 8;
        int c = n0 * 16 + (lane & 15);
        uint4 hv, lv;
        uint* hp = (uint*)&hv;
        uint* lp = (uint*)&lv;
#pragma unroll
        for (int g = 0; g < 4; g++) {
            float w0 = W[(k0 + 2 * g) * HID + c];
            float w1 = W[(k0 + 2 * g + 1) * HID + c];
            uint h0 = bf_round16(w0), h1 = bf_round16(w1);
            float r0 = w0 - __uint_as_float(h0 << 16);
            float r1 = w1 - __uint_as_float(h1 << 16);
            hp[g] = h0 | (h1 << 16);
            lp[g] = pack_bf2(r0, r1);
        }
        Bh[s * 64 + lane] = hv;
        Bl[s * 64 + lane] = lv;
    }
    __syncthreads();

    int wv = t >> 6;
    int m0w = blockIdx.x * 64 + wv * 16;           // NT % 64 == 0
    int row = m0w + (lane & 15);
    int quad = lane >> 4;

    U8 a[4];
#pragma unroll
    for (int ks = 0; ks < 4; ks++)
        a[ks].u = *(const uint4*)&hbf[(size_t)row * 64 + ks * 16 + quad * 4];

    f32x4 acc[8];
#pragma unroll
    for (int i = 0; i < 8; i++) acc[i] = (f32x4)(0.f);

#pragma unroll
    for (int ks = 0; ks < 4; ks++) {
#pragma unroll
        for (int n0 = 0; n0 < 8; n0++) {
            U8 b;
            b.u = Bh[(ks * 8 + n0) * 64 + lane];
            acc[n0] = __builtin_amdgcn_mfma_f32_16x16x32_bf16(a[ks].v, b.v, acc[n0], 0, 0, 0);
        }
#pragma unroll
        for (int n0 = 0; n0 < 8; n0++) {
            U8 b;
            b.u = Bl[(ks * 8 + n0) * 64 + lane];
            acc[n0] = __builtin_amdgcn_mfma_f32_16x16x32_bf16(a[ks].v, b.v, acc[n0], 0, 0, 0);
        }
    }

    float4 cs4 = *(const float4*)&cs[m0w + quad * 4];
    const float csr[4] = { cs4.x, cs4.y, cs4.z, cs4.w };
#pragma unroll
    for (int n0 = 0; n0 < 8; n0++) {
#pragma unroll
        for (int r = 0; r < 4; r++) {
            float v = acc[n0][r] * csr[r];
            float partner = __shfl_xor(v, 1, 64);
            if (!(lane & 1)) {
                int rg = m0w + quad * 4 + r;
                pbf[(size_t)rg * 64 + n0 * 8 + ((lane & 15) >> 1)] = pack_bf2(v, partner);
            }
        }
    }
}

// ---------------- aggregate bf16 p over incoming edges, relu, write bf16 h ----------------
__global__ __launch_bounds__(256) void agg_relu_k(const uint* __restrict__ pbf,
                                                  const int* __restrict__ row_start,
                                                  const int* __restrict__ col,
                                                  const float* __restrict__ cd,
                                                  const float* __restrict__ b,
                                                  uint* __restrict__ hbf) {
    int t = threadIdx.x;
    int lane = t & 63;
    int n = blockIdx.x * 4 + (t >> 6);
    int beg = __builtin_amdgcn_readfirstlane(row_start[n]);
    int end = __builtin_amdgcn_readfirstlane(row_start[n + 1]);
    float ax = 0.f, ay = 0.f;
    int i = beg;
    for (; i + 4 <= end; i += 4) {
        int c0 = col[i], c1 = col[i + 1], c2 = col[i + 2], c3 = col[i + 3];
        uint v0 = pbf[(size_t)c0 * 64 + lane];
        uint v1 = pbf[(size_t)c1 * 64 + lane];
        uint v2 = pbf[(size_t)c2 * 64 + lane];
        uint v3 = pbf[(size_t)c3 * 64 + lane];
        ax += bf_lo(v0) + bf_lo(v1) + bf_lo(v2) + bf_lo(v3);
        ay += bf_hi(v0) + bf_hi(v1) + bf_hi(v2) + bf_hi(v3);
    }
    for (; i < end; i++) {
        uint v = pbf[(size_t)col[i] * 64 + lane];
        ax += bf_lo(v);
        ay += bf_hi(v);
    }
    float s = cd[n];
    float r0 = fmaxf(ax * s + b[2 * lane], 0.f);
    float r1 = fmaxf(ay * s + b[2 * lane + 1], 0.f);
    hbf[(size_t)n * 64 + lane] = pack_bf2(r0, r1);
}

// ---------------- mean-pool per graph ----------------
__device__ __forceinline__ int lower_bound_seg(const int* __restrict__ seg, int val) {
    int lo = 0, hi = NN;
    while (lo < hi) {
        int m = (lo + hi) >> 1;
        if (seg[m] < val) lo = m + 1; else hi = m;
    }
    return lo;
}

__global__ __launch_bounds__(1024) void pool_k(const uint* __restrict__ hbf,
                                               const int* __restrict__ seg1, const int* __restrict__ seg2,
                                               float* __restrict__ out) {
    __shared__ int sb[2];
    __shared__ float2 buf[16 * 64];
    int g = blockIdx.x;            // 0..255
    int br = g >> 7;
    int gg = g & 127;
    const int* seg = br ? seg2 : seg1;
    int t = threadIdx.x;
    if (t < 2) sb[t] = lower_bound_seg(seg, gg + t);
    __syncthreads();
    int beg = sb[0], end = sb[1];
    int u = t & 63, part = t >> 6;   // 16 parts
    size_t base = (size_t)br * NN;
    float ax = 0.f, ay = 0.f;
    for (int n = beg + part; n < end; n += 16) {
        uint v = hbf[(base + n) * 64 + u];
        ax += bf_lo(v);
        ay += bf_hi(v);
    }
    buf[part * 64 + u] = make_float2(ax, ay);
    __syncthreads();
    if (part == 0) {
        float2 s = buf[u];
#pragma unroll
        for (int i = 1; i < 16; i++) { s.x += buf[i * 64 + u].x; s.y += buf[i * 64 + u].y; }
        float inv = 1.f / fmaxf((float)(end - beg), 1.f);
        out[g * HID + 2 * u] = s.x * inv;
        out[g * HID + 2 * u + 1] = s.y * inv;
    }
}

// ---------------- |hg1-hg2| @ Wc + bc ----------------
__global__ __launch_bounds__(128) void logits_k(const float* __restrict__ out_hg,
                                                const float* __restrict__ Wc,
                                                const float* __restrict__ bc,
                                                float* __restrict__ logits) {
    __shared__ float d[HID];
    int g = blockIdx.x;
    int t = threadIdx.x;
    d[t] = fabsf(out_hg[g * HID + t] - out_hg[NG * HID + g * HID + t]);
    __syncthreads();
    if (t < NC) {
        float a = bc[t];
        for (int k = 0; k < HID; k++) a += d[k] * Wc[k * NC + t];
        logits[g * NC + t] = a;
    }
}

extern "C" void kernel_launch(void* const* d_in, const int* in_sizes, int n_in,
                              void* d_out, int out_size, void* d_ws, size_t ws_size,
                              hipStream_t stream) {
    const int* src1 = (const int*)d_in[0];
    const int* dst1 = (const int*)d_in[1];
    const int* seg1 = (const int*)d_in[2];
    const int* src2 = (const int*)d_in[3];
    const int* dst2 = (const int*)d_in[4];
    const int* seg2 = (const int*)d_in[5];
    const float* W1 = (const float*)d_in[6];
    const float* b1 = (const float*)d_in[7];
    const float* Wl[3] = { (const float*)d_in[8], (const float*)d_in[10], (const float*)d_in[12] };
    const float* bl[3] = { (const float*)d_in[9], (const float*)d_in[11], (const float*)d_in[13] };
    const float* Wc = (const float*)d_in[14];
    const float* bc = (const float*)d_in[15];
    float* out = (float*)d_out;

    // ---- workspace layout ----
    uint* hbf = (uint*)d_ws;                        // NT*64 (bf16x2 packed h)      51.2 MB
    uint* pbf = hbf + (size_t)NT * 64;              // NT*64 (bf16x2 packed p)      51.2 MB
    uint* pairs = pbf;                              // alias: NBUK*CAP uint (16 MB, dead before gemm)
    ushort* vals = (ushort*)(pbf + (size_t)NBUK * CAP);  // NBUK*CAP ushort (8 MB)
    int* col       = (int*)(pbf + (size_t)NT * 64); // ET                           12.8 MB
    int* row_start = col + ET;                      // NT+1
    int* bbase     = row_start + NT + 2;            // NBUK
    int* bcount_d  = bbase + NBUK;                  // NBUK
    int* bcount_s  = bcount_d + NBUK;               // NBUK (contiguous for one memset)
    float* cs   = (float*)(bcount_s + NBUK);        // NT
    float* cd   = cs + NT;                          // NT
    float* s0   = cd + NT;                          // NT
    float* aggs = s0 + NT;                          // NT

    hipMemsetAsync(bcount_d, 0, 2 * NBUK * sizeof(int), stream);

    bin_dst_k<<<BINB, 256, 0, stream>>>(src1, dst1, src2, dst2, bcount_d, pairs);
    bin_src_k<<<BINB, 256, 0, stream>>>(src1, src2, bcount_s, vals);
    bucket_scan_k<<<1, 64, 0, stream>>>(bcount_d, bbase, row_start);
    build_k<<<NBUK, 256, 0, stream>>>(pairs, vals, bcount_d, bcount_s, bbase,
                                      row_start, cs, cd, s0, col);

    // layer 1 (rank-1)
    l1_agg_k<<<(NT + 255) / 256, 256, 0, stream>>>(row_start, col, s0, cd, aggs);
    l1_expand_k<<<(NT * 64) / 256, 256, 0, stream>>>(aggs, W1, b1, hbf);

    // layers 2..4 (MFMA GEMM + gather-aggregate)
    for (int l = 0; l < 3; l++) {
        gemm_k<<<NT / 64, 256, 0, stream>>>(hbf, Wl[l], cs, pbf);
        agg_relu_k<<<NT / 4, 256, 0, stream>>>(pbf, row_start, col, cd, bl[l], hbf);
    }

    // mean pool (both branches), writes hg1|hg2 directly
    pool_k<<<2 * NG, 1024, 0, stream>>>(hbf, seg1, seg2, out);

    logits_k<<<NG, 128, 0, stream>>>(out, Wc, bc, out + 2 * NG * HID);
}